// Round 1
// baseline (2164.496 us; speedup 1.0000x reference)
//
#include <hip/hip_runtime.h>

// Problem constants (fixed by setup_inputs)
#define N_NODES 8192
#define N_EDGES 65536
#define NODE_STRIDE 56   // 18 ch * 3 classes = 54, padded to 56 for 16B alignment

// Workspace layout (in floats)
#define XN3_OFF   0                         // [8192][56]
#define DXN3_OFF  (XN3_OFF + N_NODES*NODE_STRIDE)     // [8192][56]
#define M1_OFF    (DXN3_OFF + N_NODES*NODE_STRIDE)    // [5][2][36][36]
#define M2_OFF    (M1_OFF + 5*2*36*36)                // [5][2][36][36]
#define K2N_OFF   (M2_OFF + 5*2*36*36)                // [2][16][16]
#define KNC_OFF   (K2N_OFF + 2*16*16)                 // [2][3][18]
#define K2E_OFF   (KNC_OFF + 2*3*18)                  // [2]

__device__ __forceinline__ void vrelu3(float& x0, float& x1, float& x2,
                                       float q0, float q1, float q2, float iq2) {
    // w = x - relu(dot(x,Q)) * Q / |Q|^2
    float t = x0*q0 + x1*q1 + x2*q2;
    float r = t > 0.f ? t*iq2 : 0.f;
    x0 = fmaf(-r, q0, x0);
    x1 = fmaf(-r, q1, x1);
    x2 = fmaf(-r, q2, x2);
}

// matvec over channels for the 3 position classes + fused relu-projection.
// class 0 uses M0, classes 1,2 use MA (both [NC][NC], row-major o*NC+c).
template<int NC>
__device__ __forceinline__ void matvec_relu(const float (&in)[NC][3], float (&out)[NC][3],
                                            const float* __restrict__ M0,
                                            const float* __restrict__ MA,
                                            float q0, float q1, float q2, float iq2) {
#pragma unroll
    for (int o = 0; o < NC; ++o) {
        float a0 = 0.f, a1 = 0.f, a2 = 0.f;
#pragma unroll
        for (int c = 0; c < NC; ++c) {
            float m0 = M0[o*NC + c];
            float mA = MA[o*NC + c];
            a0 = fmaf(m0, in[c][0], a0);
            a1 = fmaf(mA, in[c][1], a1);
            a2 = fmaf(mA, in[c][2], a2);
        }
        float t = a0*q0 + a1*q1 + a2*q2;
        float r = t > 0.f ? t*iq2 : 0.f;
        out[o][0] = fmaf(-r, q0, a0);
        out[o][1] = fmaf(-r, q1, a1);
        out[o][2] = fmaf(-r, q2, a2);
    }
}

// ---------------- precompute reduced matrices ----------------
__global__ void precompute_kernel(const float* __restrict__ K2N,   // [16,16,6]
                                  const float* __restrict__ K2E,   // [1,1,6]
                                  const float* __restrict__ KE1,   // [5,36,36,6]
                                  const float* __restrict__ KE2,   // [5,36,36,6]
                                  const float* __restrict__ KNc,   // [3,18,6]
                                  float* __restrict__ ws) {
    int tid = blockIdx.x * blockDim.x + threadIdx.x;
    int nthr = gridDim.x * blockDim.x;
    for (int m = tid; m < 5*2*36*36; m += nthr) {
        int l = m / 2592, r = m % 2592;
        int s = r / 1296, oc = r % 1296;
        const float* p1 = KE1 + (l*1296 + oc)*6 + 3*s;
        ws[M1_OFF + m] = p1[0] + p1[1] + p1[2];
        const float* p2 = KE2 + (l*1296 + oc)*6 + 3*s;
        ws[M2_OFF + m] = p2[0] + p2[1] + p2[2];
    }
    for (int m = tid; m < 2*256; m += nthr) {
        int s = m / 256, oc = m % 256;
        const float* p = K2N + oc*6 + 3*s;
        ws[K2N_OFF + m] = p[0] + p[1] + p[2];
    }
    for (int m = tid; m < 2*54; m += nthr) {
        int s = m / 54, oc = m % 54;
        const float* p = KNc + oc*6 + 3*s;
        ws[KNC_OFF + m] = p[0] + p[1] + p[2];
    }
    if (tid < 2) {
        const float* p = K2E + 3*tid;
        ws[K2E_OFF + tid] = p[0] + p[1] + p[2];
    }
}

__global__ void zero_kernel(float* __restrict__ p, int n) {
    int t = blockIdx.x * blockDim.x + threadIdx.x;
    if (t < n) p[t] = 0.f;
}

// ---------------- node opening: double_vector_layer(xnV, K1Nopen, K2Nopen, Q) ----------------
__global__ void node_open_kernel(const float* __restrict__ xnV,   // [3,9,N]
                                 const float* __restrict__ Q,
                                 const float* __restrict__ K1N,   // [16,3,6]
                                 const float* __restrict__ ws,    // reduced K2N at K2N_OFF
                                 float* __restrict__ xn3) {
    int n = blockIdx.x * blockDim.x + threadIdx.x;
    if (n >= N_NODES) return;
    float q0 = Q[0], q1 = Q[1], q2 = Q[2];
    float iq2 = 1.f / (q0*q0 + q1*q1 + q2*q2);

    // full relu on raw [3][9]
    float R[3][9];
#pragma unroll
    for (int c = 0; c < 3; ++c)
#pragma unroll
        for (int p = 0; p < 9; ++p)
            R[c][p] = xnV[(c*9 + p)*N_NODES + n];
#pragma unroll
    for (int c = 0; c < 3; ++c)
#pragma unroll
        for (int v = 0; v < 3; ++v)
            vrelu3(R[c][3*v], R[c][3*v+1], R[c][3*v+2], q0, q1, q2, iq2);

    // full vector_layer with K1Nopen -> tiled s[16][3]
    float s[16][3];
#pragma unroll
    for (int o = 0; o < 16; ++o) {
        float a0 = 0.f, a1 = 0.f, a2 = 0.f;
#pragma unroll
        for (int c = 0; c < 3; ++c)
#pragma unroll
            for (int g = 0; g < 3; ++g) {
                a0 = fmaf(R[c][3*g + 0], K1N[(o*3 + c)*6 + g],     a0);
                a1 = fmaf(R[c][3*g + 1], K1N[(o*3 + c)*6 + 3 + g], a1);
                a2 = fmaf(R[c][3*g + 2], K1N[(o*3 + c)*6 + 3 + g], a2);
            }
        s[o][0] = a0; s[o][1] = a1; s[o][2] = a2;
    }
#pragma unroll
    for (int o = 0; o < 16; ++o)
        vrelu3(s[o][0], s[o][1], s[o][2], q0, q1, q2, iq2);

    // reduced K2Nopen + final relu
    float u[16][3];
    matvec_relu<16>(s, u, ws + K2N_OFF, ws + K2N_OFF + 256, q0, q1, q2, iq2);

    float* dst = xn3 + n*NODE_STRIDE;
#pragma unroll
    for (int o = 0; o < 16; ++o)
#pragma unroll
        for (int g = 0; g < 3; ++g)
            dst[o*3 + g] = u[o][g];
#pragma unroll
    for (int k = 48; k < NODE_STRIDE; ++k) dst[k] = 0.f;   // ch16,17 accumulated by edge_open; pads
}

// ---------------- edge opening + scatter into xn3 channels 16,17 ----------------
__global__ void edge_open_kernel(const float* __restrict__ xeV,   // [1,9,E]
                                 const int* __restrict__ iInd,
                                 const int* __restrict__ jInd,
                                 const float* __restrict__ Q,
                                 const float* __restrict__ K1E,   // [1,1,6]
                                 const float* __restrict__ ws,    // reduced K2E at K2E_OFF
                                 float* __restrict__ xn3) {
    int e = blockIdx.x * blockDim.x + threadIdx.x;
    if (e >= N_EDGES) return;
    float q0 = Q[0], q1 = Q[1], q2 = Q[2];
    float iq2 = 1.f / (q0*q0 + q1*q1 + q2*q2);

    float R[9];
#pragma unroll
    for (int p = 0; p < 9; ++p) R[p] = xeV[p*N_EDGES + e];
#pragma unroll
    for (int v = 0; v < 3; ++v)
        vrelu3(R[3*v], R[3*v+1], R[3*v+2], q0, q1, q2, iq2);

    float s0 = 0.f, s1 = 0.f, s2 = 0.f;
#pragma unroll
    for (int g = 0; g < 3; ++g) {
        s0 = fmaf(R[3*g + 0], K1E[g],     s0);
        s1 = fmaf(R[3*g + 1], K1E[3 + g], s1);
        s2 = fmaf(R[3*g + 2], K1E[3 + g], s2);
    }
    vrelu3(s0, s1, s2, q0, q1, q2, iq2);
    s0 *= ws[K2E_OFF + 0];
    s1 *= ws[K2E_OFF + 1];
    s2 *= ws[K2E_OFF + 1];
    vrelu3(s0, s1, s2, q0, q1, q2, iq2);

    int i = iInd[e], j = jInd[e];
    float xs[3] = {s0, s1, s2};
#pragma unroll
    for (int g = 0; g < 3; ++g) {
        atomicAdd(&xn3[i*NODE_STRIDE + 48 + g],  xs[g]);        // ch16 = edge_div
        atomicAdd(&xn3[j*NODE_STRIDE + 48 + g], -xs[g]);
        atomicAdd(&xn3[i*NODE_STRIDE + 51 + g],  0.5f*xs[g]);   // ch17 = edge_ave
        atomicAdd(&xn3[j*NODE_STRIDE + 51 + g],  0.5f*xs[g]);
    }
}

// ---------------- the big per-layer edge kernel ----------------
template<bool WRITE_FLUX>
__global__ __launch_bounds__(64, 1) void edge_layer_kernel(
        const float* __restrict__ xn3, float* __restrict__ dxn3,
        const int* __restrict__ iInd, const int* __restrict__ jInd,
        const float* __restrict__ Q,
        const float* __restrict__ M10, const float* __restrict__ M1A,
        const float* __restrict__ M20, const float* __restrict__ M2A,
        float* __restrict__ fluxOut) {
    int e = blockIdx.x * 64 + threadIdx.x;
    float q0 = Q[0], q1 = Q[1], q2 = Q[2];
    float iq2 = 1.f / (q0*q0 + q1*q1 + q2*q2);
    int i = iInd[e], j = jInd[e];
    const float* xi = xn3 + i*NODE_STRIDE;
    const float* xj = xn3 + j*NODE_STRIDE;

    // dxe = [grad(18); ave(18)] per class, then first relu
    float v[36][3];
#pragma unroll
    for (int c = 0; c < 18; ++c)
#pragma unroll
        for (int g = 0; g < 3; ++g) {
            float a = xi[c*3 + g], b = xj[c*3 + g];
            v[c][g]      = a - b;
            v[18 + c][g] = 0.5f*(a + b);
        }
#pragma unroll
    for (int c = 0; c < 36; ++c)
        vrelu3(v[c][0], v[c][1], v[c][2], q0, q1, q2, iq2);

    float u[36][3];
    matvec_relu<36>(v, u, M10, M1A, q0, q1, q2, iq2);
    float w[36][3];
    matvec_relu<36>(u, w, M20, M2A, q0, q1, q2, iq2);

    // scatter: dxn = edge_div(F[:18]) + edge_ave(F[18:])
    float* di = dxn3 + i*NODE_STRIDE;
    float* dj = dxn3 + j*NODE_STRIDE;
#pragma unroll
    for (int c = 0; c < 18; ++c)
#pragma unroll
        for (int g = 0; g < 3; ++g) {
            float fd = w[c][g], fa = w[18 + c][g];
            atomicAdd(&di[c*3 + g], fd + 0.5f*fa);
            atomicAdd(&dj[c*3 + g], 0.5f*fa - fd);
        }

    if (WRITE_FLUX) {
#pragma unroll
        for (int c = 0; c < 36; ++c)
#pragma unroll
            for (int p = 0; p < 9; ++p)
                fluxOut[(c*9 + p)*N_EDGES + e] = w[c][p % 3];
    }
}

// ---------------- xn update ----------------
__global__ void update_kernel(float* __restrict__ xn3, float* __restrict__ dxn3, int n) {
    int t = blockIdx.x * blockDim.x + threadIdx.x;
    if (t < n) {
        xn3[t] = fmaf(-0.1f, dxn3[t], xn3[t]);
        dxn3[t] = 0.f;
    }
}

// ---------------- closing layer: out = vector_layer(xn, KNclose) ----------------
__global__ void close_kernel(const float* __restrict__ xn3,
                             const float* __restrict__ ws,   // reduced KNclose at KNC_OFF
                             float* __restrict__ out) {
    int n = blockIdx.x * blockDim.x + threadIdx.x;
    if (n >= N_NODES) return;
    const float* x = xn3 + n*NODE_STRIDE;
    float o[3][3];
#pragma unroll
    for (int oo = 0; oo < 3; ++oo) {
        float a0 = 0.f, a1 = 0.f, a2 = 0.f;
#pragma unroll
        for (int c = 0; c < 18; ++c) {
            float m0 = ws[KNC_OFF + oo*18 + c];
            float mA = ws[KNC_OFF + 54 + oo*18 + c];
            a0 = fmaf(m0, x[c*3 + 0], a0);
            a1 = fmaf(mA, x[c*3 + 1], a1);
            a2 = fmaf(mA, x[c*3 + 2], a2);
        }
        o[oo][0] = a0; o[oo][1] = a1; o[oo][2] = a2;
    }
#pragma unroll
    for (int oo = 0; oo < 3; ++oo)
#pragma unroll
        for (int p = 0; p < 9; ++p)
            out[(oo*9 + p)*N_NODES + n] = o[oo][p % 3];
}

extern "C" void kernel_launch(void* const* d_in, const int* in_sizes, int n_in,
                              void* d_out, int out_size, void* d_ws, size_t ws_size,
                              hipStream_t stream) {
    const float* xnV = (const float*)d_in[0];
    const float* xeV = (const float*)d_in[1];
    const int*   iInd = (const int*)d_in[2];
    const int*   jInd = (const int*)d_in[3];
    const float* K1N = (const float*)d_in[4];
    const float* K2N = (const float*)d_in[5];
    const float* K1E = (const float*)d_in[6];
    const float* K2E = (const float*)d_in[7];
    const float* KE1 = (const float*)d_in[8];
    const float* KE2 = (const float*)d_in[9];
    const float* KNc = (const float*)d_in[10];
    const float* Q   = (const float*)d_in[11];

    float* ws   = (float*)d_ws;
    float* xn3  = ws + XN3_OFF;
    float* dxn3 = ws + DXN3_OFF;
    float* out  = (float*)d_out;
    float* fluxOut = out + 3*9*N_NODES;

    precompute_kernel<<<64, 256, 0, stream>>>(K2N, K2E, KE1, KE2, KNc, ws);
    zero_kernel<<<(N_NODES*NODE_STRIDE + 255)/256, 256, 0, stream>>>(dxn3, N_NODES*NODE_STRIDE);
    node_open_kernel<<<N_NODES/256, 256, 0, stream>>>(xnV, Q, K1N, ws, xn3);
    edge_open_kernel<<<N_EDGES/256, 256, 0, stream>>>(xeV, iInd, jInd, Q, K1E, ws, xn3);

    for (int l = 0; l < 5; ++l) {
        const float* M10 = ws + M1_OFF + l*2592;
        const float* M1A = M10 + 1296;
        const float* M20 = ws + M2_OFF + l*2592;
        const float* M2A = M20 + 1296;
        if (l == 4)
            edge_layer_kernel<true><<<N_EDGES/64, 64, 0, stream>>>(
                xn3, dxn3, iInd, jInd, Q, M10, M1A, M20, M2A, fluxOut);
        else
            edge_layer_kernel<false><<<N_EDGES/64, 64, 0, stream>>>(
                xn3, dxn3, iInd, jInd, Q, M10, M1A, M20, M2A, nullptr);
        update_kernel<<<(N_NODES*NODE_STRIDE + 255)/256, 256, 0, stream>>>(
            xn3, dxn3, N_NODES*NODE_STRIDE);
    }

    close_kernel<<<N_NODES/256, 256, 0, stream>>>(xn3, ws, out);
}

// Round 2
// 849.518 us; speedup vs baseline: 2.5479x; 2.5479x over previous
//
#include <hip/hip_runtime.h>

// Problem constants (fixed by setup_inputs)
#define N_NODES 8192
#define N_EDGES 65536
#define NS 56    // node state stride: 18 ch * 3 classes = 54, padded
#define FS 112   // per-edge flux stride: 2 roles * 56 (54 used each)

// Workspace layout (float offsets)
#define XN3_OFF   0                                   // [8192][56]
#define SE_OFF    (XN3_OFF + N_NODES*NS)              // [E][4] edge-open scalars
#define M1_OFF    (SE_OFF + N_EDGES*4)                // [5][2][36][36]
#define M2_OFF    (M1_OFF + 5*2*36*36)                // [5][2][36][36]
#define K2N_OFF   (M2_OFF + 5*2*36*36)                // [2][16][16]
#define KNC_OFF   (K2N_OFF + 2*16*16)                 // [2][3][18]
#define K2E_OFF   (KNC_OFF + 2*3*18)                  // [2]
#define FLUX_OFF  747440                              // 16B-aligned, [E][112]
#define FLUX_END  (FLUX_OFF + N_EDGES*FS)
// int offsets (into (int*)d_ws)
#define DEG_OFF   FLUX_END
#define RP_OFF    (DEG_OFF + N_NODES)
#define FP_OFF    (RP_OFF + N_NODES + 1)
#define ADJ_OFF   (FP_OFF + N_NODES)                  // [2*E] packed (e<<1 | isJ)

__device__ __forceinline__ void vrelu3(float& x0, float& x1, float& x2,
                                       float q0, float q1, float q2, float iq2) {
    float t = x0*q0 + x1*q1 + x2*q2;
    float r = t > 0.f ? t*iq2 : 0.f;
    x0 = fmaf(-r, q0, x0);
    x1 = fmaf(-r, q1, x1);
    x2 = fmaf(-r, q2, x2);
}

template<int NC>
__device__ __forceinline__ void matvec_relu(const float (&in)[NC][3], float (&out)[NC][3],
                                            const float* __restrict__ M0,
                                            const float* __restrict__ MA,
                                            float q0, float q1, float q2, float iq2) {
#pragma unroll
    for (int o = 0; o < NC; ++o) {
        float a0 = 0.f, a1 = 0.f, a2 = 0.f;
#pragma unroll
        for (int c = 0; c < NC; ++c) {
            float m0 = M0[o*NC + c];
            float mA = MA[o*NC + c];
            a0 = fmaf(m0, in[c][0], a0);
            a1 = fmaf(mA, in[c][1], a1);
            a2 = fmaf(mA, in[c][2], a2);
        }
        float t = a0*q0 + a1*q1 + a2*q2;
        float r = t > 0.f ? t*iq2 : 0.f;
        out[o][0] = fmaf(-r, q0, a0);
        out[o][1] = fmaf(-r, q1, a1);
        out[o][2] = fmaf(-r, q2, a2);
    }
}

// ---------------- precompute reduced matrices ----------------
__global__ void precompute_kernel(const float* __restrict__ K2N,
                                  const float* __restrict__ K2E,
                                  const float* __restrict__ KE1,
                                  const float* __restrict__ KE2,
                                  const float* __restrict__ KNc,
                                  float* __restrict__ ws) {
    int tid = blockIdx.x * blockDim.x + threadIdx.x;
    int nthr = gridDim.x * blockDim.x;
    for (int m = tid; m < 5*2*36*36; m += nthr) {
        int l = m / 2592, r = m % 2592;
        int s = r / 1296, oc = r % 1296;
        const float* p1 = KE1 + (l*1296 + oc)*6 + 3*s;
        ws[M1_OFF + m] = p1[0] + p1[1] + p1[2];
        const float* p2 = KE2 + (l*1296 + oc)*6 + 3*s;
        ws[M2_OFF + m] = p2[0] + p2[1] + p2[2];
    }
    for (int m = tid; m < 2*256; m += nthr) {
        int s = m / 256, oc = m % 256;
        const float* p = K2N + oc*6 + 3*s;
        ws[K2N_OFF + m] = p[0] + p[1] + p[2];
    }
    for (int m = tid; m < 2*54; m += nthr) {
        int s = m / 54, oc = m % 54;
        const float* p = KNc + oc*6 + 3*s;
        ws[KNC_OFF + m] = p[0] + p[1] + p[2];
    }
    if (tid < 2) {
        const float* p = K2E + 3*tid;
        ws[K2E_OFF + tid] = p[0] + p[1] + p[2];
    }
}

// ---------------- CSR build ----------------
__global__ void zero_i32_kernel(int* __restrict__ p, int n) {
    int t = blockIdx.x * blockDim.x + threadIdx.x;
    if (t < n) p[t] = 0;
}

__global__ void count_kernel(const int* __restrict__ iInd, const int* __restrict__ jInd,
                             int* __restrict__ deg) {
    int e = blockIdx.x * blockDim.x + threadIdx.x;
    if (e >= N_EDGES) return;
    atomicAdd(&deg[iInd[e]], 1);
    atomicAdd(&deg[jInd[e]], 1);
}

__global__ void scan_kernel(const int* __restrict__ deg, int* __restrict__ rowptr,
                            int* __restrict__ fpos) {
    __shared__ int lds[256];
    int t = threadIdx.x;              // 256 threads, 32 elems each
    int base = t * 32;
    int s = 0;
#pragma unroll
    for (int k = 0; k < 32; ++k) s += deg[base + k];
    lds[t] = s;
    __syncthreads();
    if (t == 0) {
        int run = 0;
        for (int k = 0; k < 256; ++k) { int v = lds[k]; lds[k] = run; run += v; }
        rowptr[N_NODES] = run;
    }
    __syncthreads();
    int off = lds[t];
#pragma unroll
    for (int k = 0; k < 32; ++k) {
        rowptr[base + k] = off;
        fpos[base + k] = off;
        off += deg[base + k];
    }
}

__global__ void fill_kernel(const int* __restrict__ iInd, const int* __restrict__ jInd,
                            int* __restrict__ fpos, int* __restrict__ adj) {
    int e = blockIdx.x * blockDim.x + threadIdx.x;
    if (e >= N_EDGES) return;
    int p = atomicAdd(&fpos[iInd[e]], 1);
    adj[p] = (e << 1);
    p = atomicAdd(&fpos[jInd[e]], 1);
    adj[p] = (e << 1) | 1;
}

// ---------------- node opening (writes channels 0..15 only) ----------------
__global__ void node_open_kernel(const float* __restrict__ xnV,
                                 const float* __restrict__ Q,
                                 const float* __restrict__ K1N,
                                 const float* __restrict__ ws,
                                 float* __restrict__ xn3) {
    int n = blockIdx.x * blockDim.x + threadIdx.x;
    if (n >= N_NODES) return;
    float q0 = Q[0], q1 = Q[1], q2 = Q[2];
    float iq2 = 1.f / (q0*q0 + q1*q1 + q2*q2);

    float R[3][9];
#pragma unroll
    for (int c = 0; c < 3; ++c)
#pragma unroll
        for (int p = 0; p < 9; ++p)
            R[c][p] = xnV[(c*9 + p)*N_NODES + n];
#pragma unroll
    for (int c = 0; c < 3; ++c)
#pragma unroll
        for (int v = 0; v < 3; ++v)
            vrelu3(R[c][3*v], R[c][3*v+1], R[c][3*v+2], q0, q1, q2, iq2);

    float s[16][3];
#pragma unroll
    for (int o = 0; o < 16; ++o) {
        float a0 = 0.f, a1 = 0.f, a2 = 0.f;
#pragma unroll
        for (int c = 0; c < 3; ++c)
#pragma unroll
            for (int g = 0; g < 3; ++g) {
                a0 = fmaf(R[c][3*g + 0], K1N[(o*3 + c)*6 + g],     a0);
                a1 = fmaf(R[c][3*g + 1], K1N[(o*3 + c)*6 + 3 + g], a1);
                a2 = fmaf(R[c][3*g + 2], K1N[(o*3 + c)*6 + 3 + g], a2);
            }
        s[o][0] = a0; s[o][1] = a1; s[o][2] = a2;
    }
#pragma unroll
    for (int o = 0; o < 16; ++o)
        vrelu3(s[o][0], s[o][1], s[o][2], q0, q1, q2, iq2);

    float u[16][3];
    matvec_relu<16>(s, u, ws + K2N_OFF, ws + K2N_OFF + 256, q0, q1, q2, iq2);

    float* dst = xn3 + n*NS;
#pragma unroll
    for (int o = 0; o < 16; ++o)
#pragma unroll
        for (int g = 0; g < 3; ++g)
            dst[o*3 + g] = u[o][g];
}

// ---------------- edge opening: per-edge scalar triple -> se[E][4] ----------------
__global__ void edge_open_kernel(const float* __restrict__ xeV,
                                 const float* __restrict__ Q,
                                 const float* __restrict__ K1E,
                                 const float* __restrict__ ws,
                                 float4* __restrict__ se4) {
    int e = blockIdx.x * blockDim.x + threadIdx.x;
    if (e >= N_EDGES) return;
    float q0 = Q[0], q1 = Q[1], q2 = Q[2];
    float iq2 = 1.f / (q0*q0 + q1*q1 + q2*q2);

    float R[9];
#pragma unroll
    for (int p = 0; p < 9; ++p) R[p] = xeV[p*N_EDGES + e];
#pragma unroll
    for (int v = 0; v < 3; ++v)
        vrelu3(R[3*v], R[3*v+1], R[3*v+2], q0, q1, q2, iq2);

    float s0 = 0.f, s1 = 0.f, s2 = 0.f;
#pragma unroll
    for (int g = 0; g < 3; ++g) {
        s0 = fmaf(R[3*g + 0], K1E[g],     s0);
        s1 = fmaf(R[3*g + 1], K1E[3 + g], s1);
        s2 = fmaf(R[3*g + 2], K1E[3 + g], s2);
    }
    vrelu3(s0, s1, s2, q0, q1, q2, iq2);
    s0 *= ws[K2E_OFF + 0];
    s1 *= ws[K2E_OFF + 1];
    s2 *= ws[K2E_OFF + 1];
    vrelu3(s0, s1, s2, q0, q1, q2, iq2);
    se4[e] = make_float4(s0, s1, s2, 0.f);
}

// gather edge-open contributions into xn3 channels 16,17 (thread per node)
__global__ void open_gather_kernel(const float4* __restrict__ se4,
                                   const int* __restrict__ adj,
                                   const int* __restrict__ rowptr,
                                   float* __restrict__ xn3) {
    int n = blockIdx.x * blockDim.x + threadIdx.x;
    if (n >= N_NODES) return;
    int beg = rowptr[n], end = rowptr[n + 1];
    float d0 = 0.f, d1 = 0.f, d2 = 0.f, a0 = 0.f, a1 = 0.f, a2 = 0.f;
    for (int d = beg; d < end; ++d) {
        int ae = adj[d];
        float sgn = (ae & 1) ? -1.f : 1.f;
        float4 s = se4[ae >> 1];
        d0 = fmaf(sgn, s.x, d0); d1 = fmaf(sgn, s.y, d1); d2 = fmaf(sgn, s.z, d2);
        a0 = fmaf(0.5f, s.x, a0); a1 = fmaf(0.5f, s.y, a1); a2 = fmaf(0.5f, s.z, a2);
    }
    float* dst = xn3 + n*NS;
    dst[48] = d0; dst[49] = d1; dst[50] = d2;
    dst[51] = a0; dst[52] = a1; dst[53] = a2;
    dst[54] = 0.f; dst[55] = 0.f;
}

// ---------------- per-layer phase A: edge compute, no atomics ----------------
template<bool WRITE_FLUX>
__global__ __launch_bounds__(256, 1) void edge_compute_kernel(
        const float* __restrict__ xn3,
        const int* __restrict__ iInd, const int* __restrict__ jInd,
        const float* __restrict__ Q,
        const float* __restrict__ M10, const float* __restrict__ M1A,
        const float* __restrict__ M20, const float* __restrict__ M2A,
        float* __restrict__ flux, float* __restrict__ fluxOut) {
    int e = blockIdx.x * blockDim.x + threadIdx.x;
    float q0 = Q[0], q1 = Q[1], q2 = Q[2];
    float iq2 = 1.f / (q0*q0 + q1*q1 + q2*q2);
    int i = iInd[e], j = jInd[e];
    const float* xi = xn3 + i*NS;
    const float* xj = xn3 + j*NS;

    float v[36][3];
#pragma unroll
    for (int c = 0; c < 18; ++c)
#pragma unroll
        for (int g = 0; g < 3; ++g) {
            float a = xi[c*3 + g], b = xj[c*3 + g];
            v[c][g]      = a - b;
            v[18 + c][g] = 0.5f*(a + b);
        }
#pragma unroll
    for (int c = 0; c < 36; ++c)
        vrelu3(v[c][0], v[c][1], v[c][2], q0, q1, q2, iq2);

    float u[36][3];
    matvec_relu<36>(v, u, M10, M1A, q0, q1, q2, iq2);
    float w[36][3];
    matvec_relu<36>(u, w, M20, M2A, q0, q1, q2, iq2);

    // store precombined endpoint contributions:
    //   pp[idx] = w_div + 0.5*w_ave   (for the i endpoint)
    //   pm[idx] = 0.5*w_ave - w_div   (for the j endpoint)
    float4* frow = (float4*)(flux + (size_t)e * FS);
#pragma unroll
    for (int k = 0; k < 14; ++k) {
        float4 a, b;
        float* pa = &a.x; float* pb = &b.x;
#pragma unroll
        for (int t = 0; t < 4; ++t) {
            int idx = 4*k + t;
            if (idx < 54) {
                int c = idx / 3, g = idx % 3;
                float fd = w[c][g], fa = 0.5f*w[18 + c][g];
                pa[t] = fd + fa;
                pb[t] = fa - fd;
            } else { pa[t] = 0.f; pb[t] = 0.f; }
        }
        frow[k]      = a;
        frow[14 + k] = b;
    }

    if (WRITE_FLUX) {
#pragma unroll
        for (int c = 0; c < 36; ++c)
#pragma unroll
            for (int p = 0; p < 9; ++p)
                fluxOut[(c*9 + p)*N_EDGES + e] = w[c][p % 3];
    }
}

// ---------------- per-layer phase B: wave-per-node gather + xn update ----------------
__global__ __launch_bounds__(64) void node_gather_kernel(
        const float* __restrict__ flux,
        const int* __restrict__ adj, const int* __restrict__ rowptr,
        float* __restrict__ xn3) {
    int n = blockIdx.x;
    int l = threadIdx.x;
    int li = l < 54 ? l : 0;
    int beg = rowptr[n], end = rowptr[n + 1];
    float acc = 0.f;
    for (int d = beg; d < end; ++d) {
        int ae = adj[d];
        const float* fr = flux + (size_t)(ae >> 1) * FS + (ae & 1) * 56;
        acc += fr[li];
    }
    if (l < 54) {
        float* x = xn3 + n*NS + l;
        *x = fmaf(-0.1f, acc, *x);
    }
}

// ---------------- closing layer ----------------
__global__ void close_kernel(const float* __restrict__ xn3,
                             const float* __restrict__ ws,
                             float* __restrict__ out) {
    int n = blockIdx.x * blockDim.x + threadIdx.x;
    if (n >= N_NODES) return;
    const float* x = xn3 + n*NS;
    float o[3][3];
#pragma unroll
    for (int oo = 0; oo < 3; ++oo) {
        float a0 = 0.f, a1 = 0.f, a2 = 0.f;
#pragma unroll
        for (int c = 0; c < 18; ++c) {
            float m0 = ws[KNC_OFF + oo*18 + c];
            float mA = ws[KNC_OFF + 54 + oo*18 + c];
            a0 = fmaf(m0, x[c*3 + 0], a0);
            a1 = fmaf(mA, x[c*3 + 1], a1);
            a2 = fmaf(mA, x[c*3 + 2], a2);
        }
        o[oo][0] = a0; o[oo][1] = a1; o[oo][2] = a2;
    }
#pragma unroll
    for (int oo = 0; oo < 3; ++oo)
#pragma unroll
        for (int p = 0; p < 9; ++p)
            out[(oo*9 + p)*N_NODES + n] = o[oo][p % 3];
}

extern "C" void kernel_launch(void* const* d_in, const int* in_sizes, int n_in,
                              void* d_out, int out_size, void* d_ws, size_t ws_size,
                              hipStream_t stream) {
    const float* xnV = (const float*)d_in[0];
    const float* xeV = (const float*)d_in[1];
    const int*   iInd = (const int*)d_in[2];
    const int*   jInd = (const int*)d_in[3];
    const float* K1N = (const float*)d_in[4];
    const float* K2N = (const float*)d_in[5];
    const float* K1E = (const float*)d_in[6];
    const float* K2E = (const float*)d_in[7];
    const float* KE1 = (const float*)d_in[8];
    const float* KE2 = (const float*)d_in[9];
    const float* KNc = (const float*)d_in[10];
    const float* Q   = (const float*)d_in[11];

    float* ws   = (float*)d_ws;
    float* xn3  = ws + XN3_OFF;
    float4* se4 = (float4*)(ws + SE_OFF);
    float* flux = ws + FLUX_OFF;
    int* wsi    = (int*)d_ws;
    int* deg    = wsi + DEG_OFF;
    int* rowptr = wsi + RP_OFF;
    int* fpos   = wsi + FP_OFF;
    int* adj    = wsi + ADJ_OFF;

    float* out  = (float*)d_out;
    float* fluxOut = out + 3*9*N_NODES;

    precompute_kernel<<<64, 256, 0, stream>>>(K2N, K2E, KE1, KE2, KNc, ws);
    zero_i32_kernel<<<(N_NODES + 255)/256, 256, 0, stream>>>(deg, N_NODES);
    count_kernel<<<N_EDGES/256, 256, 0, stream>>>(iInd, jInd, deg);
    scan_kernel<<<1, 256, 0, stream>>>(deg, rowptr, fpos);
    fill_kernel<<<N_EDGES/256, 256, 0, stream>>>(iInd, jInd, fpos, adj);

    node_open_kernel<<<N_NODES/256, 256, 0, stream>>>(xnV, Q, K1N, ws, xn3);
    edge_open_kernel<<<N_EDGES/256, 256, 0, stream>>>(xeV, Q, K1E, ws, se4);
    open_gather_kernel<<<N_NODES/256, 256, 0, stream>>>(se4, adj, rowptr, xn3);

    for (int l = 0; l < 5; ++l) {
        const float* M10 = ws + M1_OFF + l*2592;
        const float* M1A = M10 + 1296;
        const float* M20 = ws + M2_OFF + l*2592;
        const float* M2A = M20 + 1296;
        if (l == 4)
            edge_compute_kernel<true><<<N_EDGES/256, 256, 0, stream>>>(
                xn3, iInd, jInd, Q, M10, M1A, M20, M2A, flux, fluxOut);
        else
            edge_compute_kernel<false><<<N_EDGES/256, 256, 0, stream>>>(
                xn3, iInd, jInd, Q, M10, M1A, M20, M2A, flux, nullptr);
        node_gather_kernel<<<N_NODES, 64, 0, stream>>>(flux, adj, rowptr, xn3);
    }

    close_kernel<<<N_NODES/256, 256, 0, stream>>>(xn3, ws, out);
}

// Round 3
// 360.040 us; speedup vs baseline: 6.0118x; 2.3595x over previous
//
#include <hip/hip_runtime.h>

// Problem constants (fixed by setup_inputs)
#define N_NODES 8192
#define N_EDGES 65536
#define NS 56    // node state stride: 18 ch * 3 classes = 54, padded
#define FS 112   // per-edge flux stride: 2 roles * 56 (54 used each)

// Workspace layout (float offsets)
#define XN3_OFF   0                                   // [8192][56]
#define SE_OFF    (XN3_OFF + N_NODES*NS)              // [E][4] edge-open scalars
#define MIT_OFF   (SE_OFF + N_EDGES*4)                // [5][2][36][36][2] interleaved (m0,mA), [c][o] order
#define K2N_OFF   (MIT_OFF + 5*5184)                  // [2][16][16]
#define KNC_OFF   (K2N_OFF + 2*16*16)                 // [2][3][18]
#define K2E_OFF   (KNC_OFF + 2*3*18)                  // [2]
#define FLUX_OFF  747440                              // 16B-aligned, [E][112]
#define FLUX_END  (FLUX_OFF + N_EDGES*FS)
// int offsets (into (int*)d_ws)
#define DEG_OFF   FLUX_END
#define RP_OFF    (DEG_OFF + N_NODES)
#define FP_OFF    (RP_OFF + N_NODES + 1)
#define ADJ_OFF   (FP_OFF + N_NODES)                  // [2*E] packed (e<<1 | isJ)

__device__ __forceinline__ void vrelu3(float& x0, float& x1, float& x2,
                                       float q0, float q1, float q2, float iq2) {
    float t = x0*q0 + x1*q1 + x2*q2;
    float r = t > 0.f ? t*iq2 : 0.f;
    x0 = fmaf(-r, q0, x0);
    x1 = fmaf(-r, q1, x1);
    x2 = fmaf(-r, q2, x2);
}

// 4-thread-per-edge matvec: thread q computes output channels [9q, 9q+9).
// Input v (36 channels x 3 classes) is distributed: lane-group member qs owns
// channels [9qs, 9qs+9); broadcast via __shfl from the owner.
// mlds: LDS matrix, interleaved (m0, mA) at [(c*36 + o)*2].
__device__ __forceinline__ void matvec9(const float* mlds, int q, int lane,
                                        const float (&vin)[9][3], float (&acc)[9][3]) {
#pragma unroll
    for (int c = 0; c < 36; ++c) {
        const int qsrc = c / 9, ksrc = c % 9;
        int src = (lane & ~3) | qsrc;
        float b0 = __shfl(vin[ksrc][0], src, 64);
        float b1 = __shfl(vin[ksrc][1], src, 64);
        float b2 = __shfl(vin[ksrc][2], src, 64);
        const float* mrow = mlds + (c*36 + 9*q)*2;
#pragma unroll
        for (int k = 0; k < 9; ++k) {
            float m0 = mrow[2*k], mA = mrow[2*k + 1];
            acc[k][0] = fmaf(m0, b0, acc[k][0]);
            acc[k][1] = fmaf(mA, b1, acc[k][1]);
            acc[k][2] = fmaf(mA, b2, acc[k][2]);
        }
    }
}

// ---------------- precompute reduced matrices ----------------
__global__ void precompute_kernel(const float* __restrict__ K2N,
                                  const float* __restrict__ K2E,
                                  const float* __restrict__ KE1,
                                  const float* __restrict__ KE2,
                                  const float* __restrict__ KNc,
                                  float* __restrict__ ws) {
    int tid = blockIdx.x * blockDim.x + threadIdx.x;
    int nthr = gridDim.x * blockDim.x;
    // MIT: per layer l, stage st: [(c*36+o)*2] = (sum W[o,c,0:3], sum W[o,c,3:6])
    for (int m = tid; m < 5*1296; m += nthr) {
        int l = m / 1296, oc = m % 1296;
        int o = oc / 36, c = oc % 36;
        const float* p1 = KE1 + (size_t)(l*1296 + oc)*6;
        const float* p2 = KE2 + (size_t)(l*1296 + oc)*6;
        int d = MIT_OFF + l*5184 + (c*36 + o)*2;
        ws[d]          = p1[0] + p1[1] + p1[2];
        ws[d + 1]      = p1[3] + p1[4] + p1[5];
        ws[d + 2592]   = p2[0] + p2[1] + p2[2];
        ws[d + 2593]   = p2[3] + p2[4] + p2[5];
    }
    for (int m = tid; m < 2*256; m += nthr) {
        int s = m / 256, oc = m % 256;
        const float* p = K2N + oc*6 + 3*s;
        ws[K2N_OFF + m] = p[0] + p[1] + p[2];
    }
    for (int m = tid; m < 2*54; m += nthr) {
        int s = m / 54, oc = m % 54;
        const float* p = KNc + oc*6 + 3*s;
        ws[KNC_OFF + m] = p[0] + p[1] + p[2];
    }
    if (tid < 2) {
        const float* p = K2E + 3*tid;
        ws[K2E_OFF + tid] = p[0] + p[1] + p[2];
    }
}

// ---------------- CSR build ----------------
__global__ void zero_i32_kernel(int* __restrict__ p, int n) {
    int t = blockIdx.x * blockDim.x + threadIdx.x;
    if (t < n) p[t] = 0;
}

__global__ void count_kernel(const int* __restrict__ iInd, const int* __restrict__ jInd,
                             int* __restrict__ deg) {
    int e = blockIdx.x * blockDim.x + threadIdx.x;
    if (e >= N_EDGES) return;
    atomicAdd(&deg[iInd[e]], 1);
    atomicAdd(&deg[jInd[e]], 1);
}

__global__ void scan_kernel(const int* __restrict__ deg, int* __restrict__ rowptr,
                            int* __restrict__ fpos) {
    __shared__ int lds[256];
    int t = threadIdx.x;
    int base = t * 32;
    int s = 0;
#pragma unroll
    for (int k = 0; k < 32; ++k) s += deg[base + k];
    lds[t] = s;
    __syncthreads();
    if (t == 0) {
        int run = 0;
        for (int k = 0; k < 256; ++k) { int v = lds[k]; lds[k] = run; run += v; }
        rowptr[N_NODES] = run;
    }
    __syncthreads();
    int off = lds[t];
#pragma unroll
    for (int k = 0; k < 32; ++k) {
        rowptr[base + k] = off;
        fpos[base + k] = off;
        off += deg[base + k];
    }
}

__global__ void fill_kernel(const int* __restrict__ iInd, const int* __restrict__ jInd,
                            int* __restrict__ fpos, int* __restrict__ adj) {
    int e = blockIdx.x * blockDim.x + threadIdx.x;
    if (e >= N_EDGES) return;
    int p = atomicAdd(&fpos[iInd[e]], 1);
    adj[p] = (e << 1);
    p = atomicAdd(&fpos[jInd[e]], 1);
    adj[p] = (e << 1) | 1;
}

// ---------------- node opening (writes channels 0..15 only) ----------------
__global__ void node_open_kernel(const float* __restrict__ xnV,
                                 const float* __restrict__ Q,
                                 const float* __restrict__ K1N,
                                 const float* __restrict__ ws,
                                 float* __restrict__ xn3) {
    int n = blockIdx.x * blockDim.x + threadIdx.x;
    if (n >= N_NODES) return;
    float q0 = Q[0], q1 = Q[1], q2 = Q[2];
    float iq2 = 1.f / (q0*q0 + q1*q1 + q2*q2);

    float R[3][9];
#pragma unroll
    for (int c = 0; c < 3; ++c)
#pragma unroll
        for (int p = 0; p < 9; ++p)
            R[c][p] = xnV[(c*9 + p)*N_NODES + n];
#pragma unroll
    for (int c = 0; c < 3; ++c)
#pragma unroll
        for (int v = 0; v < 3; ++v)
            vrelu3(R[c][3*v], R[c][3*v+1], R[c][3*v+2], q0, q1, q2, iq2);

    float s[16][3];
#pragma unroll
    for (int o = 0; o < 16; ++o) {
        float a0 = 0.f, a1 = 0.f, a2 = 0.f;
#pragma unroll
        for (int c = 0; c < 3; ++c)
#pragma unroll
            for (int g = 0; g < 3; ++g) {
                a0 = fmaf(R[c][3*g + 0], K1N[(o*3 + c)*6 + g],     a0);
                a1 = fmaf(R[c][3*g + 1], K1N[(o*3 + c)*6 + 3 + g], a1);
                a2 = fmaf(R[c][3*g + 2], K1N[(o*3 + c)*6 + 3 + g], a2);
            }
        s[o][0] = a0; s[o][1] = a1; s[o][2] = a2;
    }
#pragma unroll
    for (int o = 0; o < 16; ++o)
        vrelu3(s[o][0], s[o][1], s[o][2], q0, q1, q2, iq2);

    // reduced K2Nopen matvec + relu
    float u[16][3];
#pragma unroll
    for (int o = 0; o < 16; ++o) {
        float a0 = 0.f, a1 = 0.f, a2 = 0.f;
#pragma unroll
        for (int c = 0; c < 16; ++c) {
            float m0 = ws[K2N_OFF + o*16 + c];
            float mA = ws[K2N_OFF + 256 + o*16 + c];
            a0 = fmaf(m0, s[c][0], a0);
            a1 = fmaf(mA, s[c][1], a1);
            a2 = fmaf(mA, s[c][2], a2);
        }
        u[o][0] = a0; u[o][1] = a1; u[o][2] = a2;
        vrelu3(u[o][0], u[o][1], u[o][2], q0, q1, q2, iq2);
    }

    float* dst = xn3 + n*NS;
#pragma unroll
    for (int o = 0; o < 16; ++o)
#pragma unroll
        for (int g = 0; g < 3; ++g)
            dst[o*3 + g] = u[o][g];
}

// ---------------- edge opening: per-edge scalar triple -> se[E][4] ----------------
__global__ void edge_open_kernel(const float* __restrict__ xeV,
                                 const float* __restrict__ Q,
                                 const float* __restrict__ K1E,
                                 const float* __restrict__ ws,
                                 float4* __restrict__ se4) {
    int e = blockIdx.x * blockDim.x + threadIdx.x;
    if (e >= N_EDGES) return;
    float q0 = Q[0], q1 = Q[1], q2 = Q[2];
    float iq2 = 1.f / (q0*q0 + q1*q1 + q2*q2);

    float R[9];
#pragma unroll
    for (int p = 0; p < 9; ++p) R[p] = xeV[p*N_EDGES + e];
#pragma unroll
    for (int v = 0; v < 3; ++v)
        vrelu3(R[3*v], R[3*v+1], R[3*v+2], q0, q1, q2, iq2);

    float s0 = 0.f, s1 = 0.f, s2 = 0.f;
#pragma unroll
    for (int g = 0; g < 3; ++g) {
        s0 = fmaf(R[3*g + 0], K1E[g],     s0);
        s1 = fmaf(R[3*g + 1], K1E[3 + g], s1);
        s2 = fmaf(R[3*g + 2], K1E[3 + g], s2);
    }
    vrelu3(s0, s1, s2, q0, q1, q2, iq2);
    s0 *= ws[K2E_OFF + 0];
    s1 *= ws[K2E_OFF + 1];
    s2 *= ws[K2E_OFF + 1];
    vrelu3(s0, s1, s2, q0, q1, q2, iq2);
    se4[e] = make_float4(s0, s1, s2, 0.f);
}

// gather edge-open contributions into xn3 channels 16,17 (thread per node)
__global__ void open_gather_kernel(const float4* __restrict__ se4,
                                   const int* __restrict__ adj,
                                   const int* __restrict__ rowptr,
                                   float* __restrict__ xn3) {
    int n = blockIdx.x * blockDim.x + threadIdx.x;
    if (n >= N_NODES) return;
    int beg = rowptr[n], end = rowptr[n + 1];
    float d0 = 0.f, d1 = 0.f, d2 = 0.f, a0 = 0.f, a1 = 0.f, a2 = 0.f;
    for (int d = beg; d < end; ++d) {
        int ae = adj[d];
        float sgn = (ae & 1) ? -1.f : 1.f;
        float4 s = se4[ae >> 1];
        d0 = fmaf(sgn, s.x, d0); d1 = fmaf(sgn, s.y, d1); d2 = fmaf(sgn, s.z, d2);
        a0 = fmaf(0.5f, s.x, a0); a1 = fmaf(0.5f, s.y, a1); a2 = fmaf(0.5f, s.z, a2);
    }
    float* dst = xn3 + n*NS;
    dst[48] = d0; dst[49] = d1; dst[50] = d2;
    dst[51] = a0; dst[52] = a1; dst[53] = a2;
    dst[54] = 0.f; dst[55] = 0.f;
}

// ---------------- per-layer phase A: 4 threads per edge ----------------
// Thread q of an edge owns channels [9q, 9q+9) of every 36-channel stage.
template<bool WRITE_FLUX>
__global__ __launch_bounds__(256, 4) void edge_compute_kernel(
        const float* __restrict__ xn3,
        const int* __restrict__ iInd, const int* __restrict__ jInd,
        const float* __restrict__ Q,
        const float* __restrict__ mitg,   // this layer's [2][1296][2] interleaved matrices
        float* __restrict__ flux, float* __restrict__ fluxOut) {
    __shared__ float mit[5184];
    {
        const float4* s4 = (const float4*)mitg;
        float4* d4 = (float4*)mit;
        for (int t = threadIdx.x; t < 1296; t += 256) d4[t] = s4[t];
    }
    __syncthreads();

    int tid = blockIdx.x * 256 + threadIdx.x;
    int e = tid >> 2, q = tid & 3;
    int lane = threadIdx.x & 63;
    float q0 = Q[0], q1 = Q[1], q2 = Q[2];
    float iq2 = 1.f / (q0*q0 + q1*q1 + q2*q2);
    int i = iInd[e], j = jInd[e];
    const float* xi = xn3 + i*NS;
    const float* xj = xn3 + j*NS;

    // gather + grad/ave + relu for own 9 channels
    int fbase = 27*(q & 1);       // channel-half float offset within node row
    bool isAve = q >= 2;
    float v[9][3];
#pragma unroll
    for (int k = 0; k < 9; ++k)
#pragma unroll
        for (int g = 0; g < 3; ++g) {
            float A = xi[fbase + 3*k + g], B = xj[fbase + 3*k + g];
            v[k][g] = isAve ? 0.5f*(A + B) : (A - B);
        }
#pragma unroll
    for (int k = 0; k < 9; ++k) vrelu3(v[k][0], v[k][1], v[k][2], q0, q1, q2, iq2);

    float acc[9][3];
#pragma unroll
    for (int k = 0; k < 9; ++k) { acc[k][0] = 0.f; acc[k][1] = 0.f; acc[k][2] = 0.f; }
    matvec9(mit, q, lane, v, acc);
#pragma unroll
    for (int k = 0; k < 9; ++k) {
        vrelu3(acc[k][0], acc[k][1], acc[k][2], q0, q1, q2, iq2);
        v[k][0] = acc[k][0]; v[k][1] = acc[k][1]; v[k][2] = acc[k][2];
        acc[k][0] = 0.f; acc[k][1] = 0.f; acc[k][2] = 0.f;
    }
    matvec9(mit + 2592, q, lane, v, acc);
#pragma unroll
    for (int k = 0; k < 9; ++k)
        vrelu3(acc[k][0], acc[k][1], acc[k][2], q0, q1, q2, iq2);

    // pack pp/pm: pp[c] = w[c] + 0.5*w[c+18] (q<2), pm[c] = 0.5*w[c+18] - w[c] (q>=2)
    float* frow = flux + (size_t)e*FS + ((q < 2) ? 27*q : 56 + 27*(q - 2));
#pragma unroll
    for (int k = 0; k < 9; ++k)
#pragma unroll
        for (int g = 0; g < 3; ++g) {
            float mine = acc[k][g];
            float other = __shfl_xor(mine, 2, 64);
            frow[3*k + g] = (q < 2) ? fmaf(0.5f, other, mine) : fmaf(0.5f, mine, -other);
        }

    if (WRITE_FLUX) {
#pragma unroll
        for (int k = 0; k < 9; ++k)
#pragma unroll
            for (int p = 0; p < 9; ++p)
                fluxOut[((size_t)((9*q + k)*9 + p))*N_EDGES + e] = acc[k][p % 3];
    }
}

// ---------------- per-layer phase B: wave-per-node gather + xn update ----------------
__global__ __launch_bounds__(64) void node_gather_kernel(
        const float* __restrict__ flux,
        const int* __restrict__ adj, const int* __restrict__ rowptr,
        float* __restrict__ xn3) {
    int n = blockIdx.x;
    int l = threadIdx.x;
    int li = l < 54 ? l : 0;
    int beg = rowptr[n], end = rowptr[n + 1];
    float acc = 0.f;
    for (int d = beg; d < end; ++d) {
        int ae = adj[d];
        const float* fr = flux + (size_t)(ae >> 1) * FS + (ae & 1) * 56;
        acc += fr[li];
    }
    if (l < 54) {
        float* x = xn3 + n*NS + l;
        *x = fmaf(-0.1f, acc, *x);
    }
}

// ---------------- closing layer ----------------
__global__ void close_kernel(const float* __restrict__ xn3,
                             const float* __restrict__ ws,
                             float* __restrict__ out) {
    int n = blockIdx.x * blockDim.x + threadIdx.x;
    if (n >= N_NODES) return;
    const float* x = xn3 + n*NS;
    float o[3][3];
#pragma unroll
    for (int oo = 0; oo < 3; ++oo) {
        float a0 = 0.f, a1 = 0.f, a2 = 0.f;
#pragma unroll
        for (int c = 0; c < 18; ++c) {
            float m0 = ws[KNC_OFF + oo*18 + c];
            float mA = ws[KNC_OFF + 54 + oo*18 + c];
            a0 = fmaf(m0, x[c*3 + 0], a0);
            a1 = fmaf(mA, x[c*3 + 1], a1);
            a2 = fmaf(mA, x[c*3 + 2], a2);
        }
        o[oo][0] = a0; o[oo][1] = a1; o[oo][2] = a2;
    }
#pragma unroll
    for (int oo = 0; oo < 3; ++oo)
#pragma unroll
        for (int p = 0; p < 9; ++p)
            out[(oo*9 + p)*N_NODES + n] = o[oo][p % 3];
}

extern "C" void kernel_launch(void* const* d_in, const int* in_sizes, int n_in,
                              void* d_out, int out_size, void* d_ws, size_t ws_size,
                              hipStream_t stream) {
    const float* xnV = (const float*)d_in[0];
    const float* xeV = (const float*)d_in[1];
    const int*   iInd = (const int*)d_in[2];
    const int*   jInd = (const int*)d_in[3];
    const float* K1N = (const float*)d_in[4];
    const float* K2N = (const float*)d_in[5];
    const float* K1E = (const float*)d_in[6];
    const float* K2E = (const float*)d_in[7];
    const float* KE1 = (const float*)d_in[8];
    const float* KE2 = (const float*)d_in[9];
    const float* KNc = (const float*)d_in[10];
    const float* Q   = (const float*)d_in[11];

    float* ws   = (float*)d_ws;
    float* xn3  = ws + XN3_OFF;
    float4* se4 = (float4*)(ws + SE_OFF);
    float* flux = ws + FLUX_OFF;
    int* wsi    = (int*)d_ws;
    int* deg    = wsi + DEG_OFF;
    int* rowptr = wsi + RP_OFF;
    int* fpos   = wsi + FP_OFF;
    int* adj    = wsi + ADJ_OFF;

    float* out  = (float*)d_out;
    float* fluxOut = out + 3*9*N_NODES;

    precompute_kernel<<<64, 256, 0, stream>>>(K2N, K2E, KE1, KE2, KNc, ws);
    zero_i32_kernel<<<(N_NODES + 255)/256, 256, 0, stream>>>(deg, N_NODES);
    count_kernel<<<N_EDGES/256, 256, 0, stream>>>(iInd, jInd, deg);
    scan_kernel<<<1, 256, 0, stream>>>(deg, rowptr, fpos);
    fill_kernel<<<N_EDGES/256, 256, 0, stream>>>(iInd, jInd, fpos, adj);

    node_open_kernel<<<N_NODES/256, 256, 0, stream>>>(xnV, Q, K1N, ws, xn3);
    edge_open_kernel<<<N_EDGES/256, 256, 0, stream>>>(xeV, Q, K1E, ws, se4);
    open_gather_kernel<<<N_NODES/256, 256, 0, stream>>>(se4, adj, rowptr, xn3);

    for (int l = 0; l < 5; ++l) {
        const float* mitg = ws + MIT_OFF + l*5184;
        if (l == 4)
            edge_compute_kernel<true><<<N_EDGES*4/256, 256, 0, stream>>>(
                xn3, iInd, jInd, Q, mitg, flux, fluxOut);
        else
            edge_compute_kernel<false><<<N_EDGES*4/256, 256, 0, stream>>>(
                xn3, iInd, jInd, Q, mitg, flux, nullptr);
        node_gather_kernel<<<N_NODES, 64, 0, stream>>>(flux, adj, rowptr, xn3);
    }

    close_kernel<<<N_NODES/256, 256, 0, stream>>>(xn3, ws, out);
}

// Round 4
// 312.213 us; speedup vs baseline: 6.9328x; 1.1532x over previous
//
#include <hip/hip_runtime.h>

// Problem constants (fixed by setup_inputs)
#define N_NODES 8192
#define N_EDGES 65536
#define NS 56    // node state: 2 halves of 28 floats (27 used + pad), ch c class g at (c/9)*28+(c%9)*3+g
#define FS 112   // per-edge flux: 4 rows of 28 floats: row q<2 = pp half q, row q>=2 = pm half q-2

// Workspace layout (float offsets)
#define XN3_OFF   0                                   // [8192][56]
#define SE_OFF    (N_NODES*NS)                        // [E][4] edge-open scalars
#define MIT_OFF   (SE_OFF + N_EDGES*4)                // [5][2 stages][36 c][4 q][20] padded rows
#define K2N_OFF   (MIT_OFF + 5*5760)                  // [2][16][16]
#define KNC_OFF   (K2N_OFF + 2*16*16)                 // [2][3][18]
#define K2E_OFF   (KNC_OFF + 2*3*18)                  // [2]
#define FLUX_OFF  750320                              // 16B-aligned, [E][112]
#define FLUX_END  (FLUX_OFF + N_EDGES*FS)
// int offsets (into (int*)d_ws)
#define DEG_OFF   FLUX_END
#define RP_OFF    (DEG_OFF + N_NODES)
#define FP_OFF    (RP_OFF + N_NODES + 1)
#define ADJ_OFF   (FP_OFF + N_NODES)                  // [2*E] packed (e<<1 | isJ)

typedef float f32x2 __attribute__((ext_vector_type(2)));

// quad-perm broadcast of slot SLOT within each aligned 4-lane group (VALU DPP, no LDS)
template<int SLOT>
__device__ __forceinline__ float qb(float x) {
    int r = __builtin_amdgcn_update_dpp(0, __float_as_int(x), SLOT * 0x55, 0xf, 0xf, true);
    return __int_as_float(r);
}
// quad-perm [2,3,0,1]: exchange lanes q <-> q^2
__device__ __forceinline__ float qswap2(float x) {
    int r = __builtin_amdgcn_update_dpp(0, __float_as_int(x), 0x4E, 0xf, 0xf, true);
    return __int_as_float(r);
}

__device__ __forceinline__ void vrelu_p(float& a0, f32x2& a12,
                                        float q0, f32x2 q12, float iq2) {
    float t = fmaf(a0, q0, fmaf(a12.x, q12.x, a12.y * q12.y));
    float r = t > 0.f ? t * iq2 : 0.f;
    a0 = fmaf(-r, q0, a0);
    f32x2 nr = {-r, -r};
    a12 = nr * q12 + a12;
}

__device__ __forceinline__ void vrelu3(float& x0, float& x1, float& x2,
                                       float q0, float q1, float q2, float iq2) {
    float t = x0*q0 + x1*q1 + x2*q2;
    float r = t > 0.f ? t*iq2 : 0.f;
    x0 = fmaf(-r, q0, x0);
    x1 = fmaf(-r, q1, x1);
    x2 = fmaf(-r, q2, x2);
}

__device__ __forceinline__ void ld28(const float4* __restrict__ p, float (&d)[28]) {
#pragma unroll
    for (int t = 0; t < 7; ++t) {
        float4 r = p[t];
        d[4*t] = r.x; d[4*t+1] = r.y; d[4*t+2] = r.z; d[4*t+3] = r.w;
    }
}

// one quarter of the 36-channel matvec: input channels [QS*9, QS*9+9) broadcast
// from quad slot QS; this thread accumulates its own 9 output channels.
template<int QS>
__device__ __forceinline__ void matvec_part(const float* __restrict__ mbase, int q,
        const float (&v0)[9], const f32x2 (&v12)[9],
        float (&a0)[9], f32x2 (&a12)[9]) {
    const float* rb = mbase + QS*720 + q*20;
#pragma unroll
    for (int kc = 0; kc < 9; ++kc) {
        float b0 = qb<QS>(v0[kc]);
        f32x2 b12; b12.x = qb<QS>(v12[kc].x); b12.y = qb<QS>(v12[kc].y);
        const float4* rp = (const float4*)(rb + kc*80);
        float4 R0 = rp[0], R1 = rp[1], R2 = rp[2], R3 = rp[3], R4 = rp[4];
        float m0[9] = {R0.x,R0.y,R0.z,R0.w,R1.x,R1.y,R1.z,R1.w,R2.x};
        float mA[9] = {R2.z,R2.w,R3.x,R3.y,R3.z,R3.w,R4.x,R4.y,R4.z};
#pragma unroll
        for (int k = 0; k < 9; ++k) {
            a0[k] = fmaf(m0[k], b0, a0[k]);
            f32x2 mm = {mA[k], mA[k]};
            a12[k] = mm * b12 + a12[k];
        }
    }
}

// ---------------- precompute reduced matrices ----------------
__global__ void precompute_kernel(const float* __restrict__ K2N,
                                  const float* __restrict__ K2E,
                                  const float* __restrict__ KE1,
                                  const float* __restrict__ KE2,
                                  const float* __restrict__ KNc,
                                  float* __restrict__ ws) {
    int tid = blockIdx.x * blockDim.x + threadIdx.x;
    int nthr = gridDim.x * blockDim.x;
    // zero row pads (indices 9, 19 of each 20-float row)
    for (int m = tid; m < 1440; m += nthr) {
        ws[MIT_OFF + m*20 + 9]  = 0.f;
        ws[MIT_OFF + m*20 + 19] = 0.f;
    }
    for (int m = tid; m < 5*1296; m += nthr) {
        int l = m / 1296, oc = m % 1296;
        int o = oc / 36, c = oc % 36;
        int qq = o / 9, k = o % 9;
        const float* p1 = KE1 + (size_t)(l*1296 + oc)*6;
        const float* p2 = KE2 + (size_t)(l*1296 + oc)*6;
        int base = MIT_OFF + l*5760 + (c*4 + qq)*20;
        ws[base + k]             = p1[0] + p1[1] + p1[2];
        ws[base + 10 + k]        = p1[3] + p1[4] + p1[5];
        ws[base + 2880 + k]      = p2[0] + p2[1] + p2[2];
        ws[base + 2880 + 10 + k] = p2[3] + p2[4] + p2[5];
    }
    for (int m = tid; m < 2*256; m += nthr) {
        int s = m / 256, oc = m % 256;
        const float* p = K2N + oc*6 + 3*s;
        ws[K2N_OFF + m] = p[0] + p[1] + p[2];
    }
    for (int m = tid; m < 2*54; m += nthr) {
        int s = m / 54, oc = m % 54;
        const float* p = KNc + oc*6 + 3*s;
        ws[KNC_OFF + m] = p[0] + p[1] + p[2];
    }
    if (tid < 2) {
        const float* p = K2E + 3*tid;
        ws[K2E_OFF + tid] = p[0] + p[1] + p[2];
    }
}

// ---------------- CSR build ----------------
__global__ void zero_i32_kernel(int* __restrict__ p, int n) {
    int t = blockIdx.x * blockDim.x + threadIdx.x;
    if (t < n) p[t] = 0;
}

__global__ void count_kernel(const int* __restrict__ iInd, const int* __restrict__ jInd,
                             int* __restrict__ deg) {
    int e = blockIdx.x * blockDim.x + threadIdx.x;
    if (e >= N_EDGES) return;
    atomicAdd(&deg[iInd[e]], 1);
    atomicAdd(&deg[jInd[e]], 1);
}

__global__ void scan_kernel(const int* __restrict__ deg, int* __restrict__ rowptr,
                            int* __restrict__ fpos) {
    __shared__ int lds[256];
    int t = threadIdx.x;
    int base = t * 32;
    int s = 0;
#pragma unroll
    for (int k = 0; k < 32; ++k) s += deg[base + k];
    lds[t] = s;
    __syncthreads();
    if (t == 0) {
        int run = 0;
        for (int k = 0; k < 256; ++k) { int v = lds[k]; lds[k] = run; run += v; }
        rowptr[N_NODES] = run;
    }
    __syncthreads();
    int off = lds[t];
#pragma unroll
    for (int k = 0; k < 32; ++k) {
        rowptr[base + k] = off;
        fpos[base + k] = off;
        off += deg[base + k];
    }
}

__global__ void fill_kernel(const int* __restrict__ iInd, const int* __restrict__ jInd,
                            int* __restrict__ fpos, int* __restrict__ adj) {
    int e = blockIdx.x * blockDim.x + threadIdx.x;
    if (e >= N_EDGES) return;
    int p = atomicAdd(&fpos[iInd[e]], 1);
    adj[p] = (e << 1);
    p = atomicAdd(&fpos[jInd[e]], 1);
    adj[p] = (e << 1) | 1;
}

// ---------------- node opening (writes channels 0..15) ----------------
__global__ void node_open_kernel(const float* __restrict__ xnV,
                                 const float* __restrict__ Q,
                                 const float* __restrict__ K1N,
                                 const float* __restrict__ ws,
                                 float* __restrict__ xn3) {
    int n = blockIdx.x * blockDim.x + threadIdx.x;
    if (n >= N_NODES) return;
    float q0 = Q[0], q1 = Q[1], q2 = Q[2];
    float iq2 = 1.f / (q0*q0 + q1*q1 + q2*q2);

    float R[3][9];
#pragma unroll
    for (int c = 0; c < 3; ++c)
#pragma unroll
        for (int p = 0; p < 9; ++p)
            R[c][p] = xnV[(c*9 + p)*N_NODES + n];
#pragma unroll
    for (int c = 0; c < 3; ++c)
#pragma unroll
        for (int v = 0; v < 3; ++v)
            vrelu3(R[c][3*v], R[c][3*v+1], R[c][3*v+2], q0, q1, q2, iq2);

    float s[16][3];
#pragma unroll
    for (int o = 0; o < 16; ++o) {
        float a0 = 0.f, a1 = 0.f, a2 = 0.f;
#pragma unroll
        for (int c = 0; c < 3; ++c)
#pragma unroll
            for (int g = 0; g < 3; ++g) {
                a0 = fmaf(R[c][3*g + 0], K1N[(o*3 + c)*6 + g],     a0);
                a1 = fmaf(R[c][3*g + 1], K1N[(o*3 + c)*6 + 3 + g], a1);
                a2 = fmaf(R[c][3*g + 2], K1N[(o*3 + c)*6 + 3 + g], a2);
            }
        s[o][0] = a0; s[o][1] = a1; s[o][2] = a2;
    }
#pragma unroll
    for (int o = 0; o < 16; ++o)
        vrelu3(s[o][0], s[o][1], s[o][2], q0, q1, q2, iq2);

    float u[16][3];
#pragma unroll
    for (int o = 0; o < 16; ++o) {
        float a0 = 0.f, a1 = 0.f, a2 = 0.f;
#pragma unroll
        for (int c = 0; c < 16; ++c) {
            float m0 = ws[K2N_OFF + o*16 + c];
            float mA = ws[K2N_OFF + 256 + o*16 + c];
            a0 = fmaf(m0, s[c][0], a0);
            a1 = fmaf(mA, s[c][1], a1);
            a2 = fmaf(mA, s[c][2], a2);
        }
        u[o][0] = a0; u[o][1] = a1; u[o][2] = a2;
        vrelu3(u[o][0], u[o][1], u[o][2], q0, q1, q2, iq2);
    }

    float* dst = xn3 + n*NS;
#pragma unroll
    for (int o = 0; o < 16; ++o) {
        int base = (o/9)*28 + (o%9)*3;
#pragma unroll
        for (int g = 0; g < 3; ++g)
            dst[base + g] = u[o][g];
    }
    dst[27] = 0.f;
}

// ---------------- edge opening: per-edge scalar triple -> se[E][4] ----------------
__global__ void edge_open_kernel(const float* __restrict__ xeV,
                                 const float* __restrict__ Q,
                                 const float* __restrict__ K1E,
                                 const float* __restrict__ ws,
                                 float4* __restrict__ se4) {
    int e = blockIdx.x * blockDim.x + threadIdx.x;
    if (e >= N_EDGES) return;
    float q0 = Q[0], q1 = Q[1], q2 = Q[2];
    float iq2 = 1.f / (q0*q0 + q1*q1 + q2*q2);

    float R[9];
#pragma unroll
    for (int p = 0; p < 9; ++p) R[p] = xeV[p*N_EDGES + e];
#pragma unroll
    for (int v = 0; v < 3; ++v)
        vrelu3(R[3*v], R[3*v+1], R[3*v+2], q0, q1, q2, iq2);

    float s0 = 0.f, s1 = 0.f, s2 = 0.f;
#pragma unroll
    for (int g = 0; g < 3; ++g) {
        s0 = fmaf(R[3*g + 0], K1E[g],     s0);
        s1 = fmaf(R[3*g + 1], K1E[3 + g], s1);
        s2 = fmaf(R[3*g + 2], K1E[3 + g], s2);
    }
    vrelu3(s0, s1, s2, q0, q1, q2, iq2);
    s0 *= ws[K2E_OFF + 0];
    s1 *= ws[K2E_OFF + 1];
    s2 *= ws[K2E_OFF + 1];
    vrelu3(s0, s1, s2, q0, q1, q2, iq2);
    se4[e] = make_float4(s0, s1, s2, 0.f);
}

// gather edge-open contributions into xn3 channels 16,17 (thread per node)
__global__ void open_gather_kernel(const float4* __restrict__ se4,
                                   const int* __restrict__ adj,
                                   const int* __restrict__ rowptr,
                                   float* __restrict__ xn3) {
    int n = blockIdx.x * blockDim.x + threadIdx.x;
    if (n >= N_NODES) return;
    int beg = rowptr[n], end = rowptr[n + 1];
    float d0 = 0.f, d1 = 0.f, d2 = 0.f, a0 = 0.f, a1 = 0.f, a2 = 0.f;
    for (int d = beg; d < end; ++d) {
        int ae = adj[d];
        float sgn = (ae & 1) ? -1.f : 1.f;
        float4 s = se4[ae >> 1];
        d0 = fmaf(sgn, s.x, d0); d1 = fmaf(sgn, s.y, d1); d2 = fmaf(sgn, s.z, d2);
        a0 = fmaf(0.5f, s.x, a0); a1 = fmaf(0.5f, s.y, a1); a2 = fmaf(0.5f, s.z, a2);
    }
    float* dst = xn3 + n*NS;
    // ch16 -> half1 idx 49..51, ch17 -> 52..54, pad 55
    dst[49] = d0; dst[50] = d1; dst[51] = d2;
    dst[52] = a0; dst[53] = a1; dst[54] = a2;
    dst[55] = 0.f;
}

// ---------------- per-layer phase A: 4 threads per edge, DPP broadcast ----------------
template<bool WRITE_FLUX>
__global__ __launch_bounds__(256, 4) void edge_compute_kernel(
        const float* __restrict__ xn3,
        const int* __restrict__ iInd, const int* __restrict__ jInd,
        const float* __restrict__ Q,
        const float* __restrict__ mitg,   // [2][36][4][20]
        float* __restrict__ flux, float* __restrict__ fluxOut) {
    __shared__ float mit[5760];
    {
        const float4* s4 = (const float4*)mitg;
        float4* d4 = (float4*)mit;
        for (int t = threadIdx.x; t < 1440; t += 256) d4[t] = s4[t];
    }
    __syncthreads();

    int tid = blockIdx.x * 256 + threadIdx.x;
    int e = tid >> 2, q = tid & 3;
    float q0 = Q[0];
    f32x2 q12 = {Q[1], Q[2]};
    float iq2 = 1.f / (q0*q0 + q12.x*q12.x + q12.y*q12.y);
    int i = iInd[e], j = jInd[e];
    const float4* xi = (const float4*)(xn3 + i*NS + 28*(q & 1));
    const float4* xj = (const float4*)(xn3 + j*NS + 28*(q & 1));

    float A[28], B[28];
    ld28(xi, A);
    ld28(xj, B);

    bool isAve = q >= 2;
    float sA = isAve ? 0.5f :  1.f;
    float sB = isAve ? 0.5f : -1.f;
    float v0[9]; f32x2 v12[9];
#pragma unroll
    for (int k = 0; k < 9; ++k) {
        v0[k]    = fmaf(sA, A[3*k],   sB * B[3*k]);
        v12[k].x = fmaf(sA, A[3*k+1], sB * B[3*k+1]);
        v12[k].y = fmaf(sA, A[3*k+2], sB * B[3*k+2]);
        vrelu_p(v0[k], v12[k], q0, q12, iq2);
    }

    float a0[9]; f32x2 a12[9];
#pragma unroll
    for (int k = 0; k < 9; ++k) { a0[k] = 0.f; a12[k] = (f32x2){0.f, 0.f}; }
    matvec_part<0>(mit, q, v0, v12, a0, a12);
    matvec_part<1>(mit, q, v0, v12, a0, a12);
    matvec_part<2>(mit, q, v0, v12, a0, a12);
    matvec_part<3>(mit, q, v0, v12, a0, a12);
#pragma unroll
    for (int k = 0; k < 9; ++k) {
        vrelu_p(a0[k], a12[k], q0, q12, iq2);
        v0[k] = a0[k]; v12[k] = a12[k];
        a0[k] = 0.f; a12[k] = (f32x2){0.f, 0.f};
    }
    matvec_part<0>(mit + 2880, q, v0, v12, a0, a12);
    matvec_part<1>(mit + 2880, q, v0, v12, a0, a12);
    matvec_part<2>(mit + 2880, q, v0, v12, a0, a12);
    matvec_part<3>(mit + 2880, q, v0, v12, a0, a12);
#pragma unroll
    for (int k = 0; k < 9; ++k)
        vrelu_p(a0[k], a12[k], q0, q12, iq2);

    // pp (q<2): own(div) + 0.5*partner(ave);  pm (q>=2): 0.5*own(ave) - partner(div)
    float selO = (q < 2) ? 1.f  : 0.5f;
    float selP = (q < 2) ? 0.5f : -1.f;
    float outv[28];
#pragma unroll
    for (int k = 0; k < 9; ++k) {
        float o0 = qswap2(a0[k]);
        float o1 = qswap2(a12[k].x);
        float o2 = qswap2(a12[k].y);
        outv[3*k]   = fmaf(selO, a0[k],    selP * o0);
        outv[3*k+1] = fmaf(selO, a12[k].x, selP * o1);
        outv[3*k+2] = fmaf(selO, a12[k].y, selP * o2);
    }
    outv[27] = 0.f;
    float4* frow = (float4*)(flux + (size_t)e*FS + q*28);
#pragma unroll
    for (int t = 0; t < 7; ++t)
        frow[t] = make_float4(outv[4*t], outv[4*t+1], outv[4*t+2], outv[4*t+3]);

    if (WRITE_FLUX) {
#pragma unroll
        for (int k = 0; k < 9; ++k) {
#pragma unroll
            for (int p = 0; p < 9; ++p) {
                float wv = (p % 3 == 0) ? a0[k] : (p % 3 == 1) ? a12[k].x : a12[k].y;
                fluxOut[((size_t)((9*q + k)*9 + p))*N_EDGES + e] = wv;
            }
        }
    }
}

// ---------------- per-layer phase B: wave-per-node gather + xn update ----------------
__global__ __launch_bounds__(64) void node_gather_kernel(
        const float* __restrict__ flux,
        const int* __restrict__ adj, const int* __restrict__ rowptr,
        float* __restrict__ xn3) {
    int n = blockIdx.x;
    int l = threadIdx.x;
    if (l >= 54) return;
    int idx = l + (l >= 27 ? 1 : 0);   // skip pad at 27
    int beg = rowptr[n], end = rowptr[n + 1];
    float acc = 0.f;
    for (int d = beg; d < end; ++d) {
        int ae = adj[d];
        acc += flux[(size_t)(ae >> 1)*FS + (ae & 1)*56 + idx];
    }
    float* x = xn3 + n*NS + idx;
    *x = fmaf(-0.1f, acc, *x);
}

// ---------------- closing layer ----------------
__global__ void close_kernel(const float* __restrict__ xn3,
                             const float* __restrict__ ws,
                             float* __restrict__ out) {
    int n = blockIdx.x * blockDim.x + threadIdx.x;
    if (n >= N_NODES) return;
    const float* x = xn3 + n*NS;
    float o[3][3];
#pragma unroll
    for (int oo = 0; oo < 3; ++oo) {
        float a0 = 0.f, a1 = 0.f, a2 = 0.f;
#pragma unroll
        for (int c = 0; c < 18; ++c) {
            int xidx = (c/9)*28 + (c%9)*3;
            float m0 = ws[KNC_OFF + oo*18 + c];
            float mA = ws[KNC_OFF + 54 + oo*18 + c];
            a0 = fmaf(m0, x[xidx + 0], a0);
            a1 = fmaf(mA, x[xidx + 1], a1);
            a2 = fmaf(mA, x[xidx + 2], a2);
        }
        o[oo][0] = a0; o[oo][1] = a1; o[oo][2] = a2;
    }
#pragma unroll
    for (int oo = 0; oo < 3; ++oo)
#pragma unroll
        for (int p = 0; p < 9; ++p)
            out[(oo*9 + p)*N_NODES + n] = o[oo][p % 3];
}

extern "C" void kernel_launch(void* const* d_in, const int* in_sizes, int n_in,
                              void* d_out, int out_size, void* d_ws, size_t ws_size,
                              hipStream_t stream) {
    const float* xnV = (const float*)d_in[0];
    const float* xeV = (const float*)d_in[1];
    const int*   iInd = (const int*)d_in[2];
    const int*   jInd = (const int*)d_in[3];
    const float* K1N = (const float*)d_in[4];
    const float* K2N = (const float*)d_in[5];
    const float* K1E = (const float*)d_in[6];
    const float* K2E = (const float*)d_in[7];
    const float* KE1 = (const float*)d_in[8];
    const float* KE2 = (const float*)d_in[9];
    const float* KNc = (const float*)d_in[10];
    const float* Q   = (const float*)d_in[11];

    float* ws   = (float*)d_ws;
    float* xn3  = ws + XN3_OFF;
    float4* se4 = (float4*)(ws + SE_OFF);
    float* flux = ws + FLUX_OFF;
    int* wsi    = (int*)d_ws;
    int* deg    = wsi + DEG_OFF;
    int* rowptr = wsi + RP_OFF;
    int* fpos   = wsi + FP_OFF;
    int* adj    = wsi + ADJ_OFF;

    float* out  = (float*)d_out;
    float* fluxOut = out + 3*9*N_NODES;

    precompute_kernel<<<64, 256, 0, stream>>>(K2N, K2E, KE1, KE2, KNc, ws);
    zero_i32_kernel<<<(N_NODES + 255)/256, 256, 0, stream>>>(deg, N_NODES);
    count_kernel<<<N_EDGES/256, 256, 0, stream>>>(iInd, jInd, deg);
    scan_kernel<<<1, 256, 0, stream>>>(deg, rowptr, fpos);
    fill_kernel<<<N_EDGES/256, 256, 0, stream>>>(iInd, jInd, fpos, adj);

    node_open_kernel<<<N_NODES/256, 256, 0, stream>>>(xnV, Q, K1N, ws, xn3);
    edge_open_kernel<<<N_EDGES/256, 256, 0, stream>>>(xeV, Q, K1E, ws, se4);
    open_gather_kernel<<<N_NODES/256, 256, 0, stream>>>(se4, adj, rowptr, xn3);

    for (int l = 0; l < 5; ++l) {
        const float* mitg = ws + MIT_OFF + l*5760;
        if (l == 4)
            edge_compute_kernel<true><<<N_EDGES*4/256, 256, 0, stream>>>(
                xn3, iInd, jInd, Q, mitg, flux, fluxOut);
        else
            edge_compute_kernel<false><<<N_EDGES*4/256, 256, 0, stream>>>(
                xn3, iInd, jInd, Q, mitg, flux, nullptr);
        node_gather_kernel<<<N_NODES, 64, 0, stream>>>(flux, adj, rowptr, xn3);
    }

    close_kernel<<<N_NODES/256, 256, 0, stream>>>(xn3, ws, out);
}

// Round 5
// 307.323 us; speedup vs baseline: 7.0431x; 1.0159x over previous
//
#include <hip/hip_runtime.h>

// Problem constants (fixed by setup_inputs)
#define N_NODES 8192
#define N_EDGES 65536
#define NS 56    // node state: 2 halves of 28 floats (27 used + pad); ch c class g at (c/9)*28+(c%9)*3+g
// flux: CSR-slot layout [2E slots][56] — slot s holds one edge-endpoint contribution (two 28-float halves)

// Workspace layout (float offsets)
#define XN3_OFF   0                                   // [8192][56]
#define MIT_OFF   (N_NODES*NS)                        // [5][2 stages][36 c][4 q][20] padded rows
#define K2N_OFF   (MIT_OFF + 5*5760)                  // [2][16][16]
#define KNC_OFF   (K2N_OFF + 2*16*16)                 // [2][3][18]
#define K2E_OFF   (KNC_OFF + 2*3*18)                  // [2]
#define FLUX_OFF  488192                              // 16B-aligned; [2E][56] floats (open phase reuses as [2E][8])
#define FLUX_END  (FLUX_OFF + 2*N_EDGES*56)
// int offsets (into (int*)d_ws)
#define DEG_OFF   FLUX_END
#define RP_OFF    (DEG_OFF + N_NODES)
#define FP_OFF    (RP_OFF + N_NODES + 1)
#define POSI_OFF  (FP_OFF + N_NODES)
#define POSJ_OFF  (POSI_OFF + N_EDGES)

typedef float f32x2 __attribute__((ext_vector_type(2)));

// quad-perm broadcast of slot SLOT within each aligned 4-lane group (VALU DPP, no LDS)
template<int SLOT>
__device__ __forceinline__ float qb(float x) {
    int r = __builtin_amdgcn_update_dpp(0, __float_as_int(x), SLOT * 0x55, 0xf, 0xf, true);
    return __int_as_float(r);
}
// quad-perm [2,3,0,1]: exchange lanes q <-> q^2
__device__ __forceinline__ float qswap2(float x) {
    int r = __builtin_amdgcn_update_dpp(0, __float_as_int(x), 0x4E, 0xf, 0xf, true);
    return __int_as_float(r);
}

__device__ __forceinline__ void vrelu_p(float& a0, f32x2& a12,
                                        float q0, f32x2 q12, float iq2) {
    float t = fmaf(a0, q0, fmaf(a12.x, q12.x, a12.y * q12.y));
    float r = t > 0.f ? t * iq2 : 0.f;
    a0 = fmaf(-r, q0, a0);
    f32x2 nr = {-r, -r};
    a12 = nr * q12 + a12;
}

__device__ __forceinline__ void vrelu3(float& x0, float& x1, float& x2,
                                       float q0, float q1, float q2, float iq2) {
    float t = x0*q0 + x1*q1 + x2*q2;
    float r = t > 0.f ? t*iq2 : 0.f;
    x0 = fmaf(-r, q0, x0);
    x1 = fmaf(-r, q1, x1);
    x2 = fmaf(-r, q2, x2);
}

__device__ __forceinline__ void ld28(const float4* __restrict__ p, float (&d)[28]) {
#pragma unroll
    for (int t = 0; t < 7; ++t) {
        float4 r = p[t];
        d[4*t] = r.x; d[4*t+1] = r.y; d[4*t+2] = r.z; d[4*t+3] = r.w;
    }
}

// one quarter of the 36-channel matvec: input channels [QS*9, QS*9+9) broadcast
// from quad slot QS; this thread accumulates its own 9 output channels.
// class 0 accumulators packed as 4x f32x2 + 1 scalar (v_pk_fma_f32).
template<int QS>
__device__ __forceinline__ void matvec_part(const float* __restrict__ mbase, int q,
        const float (&v0)[9], const f32x2 (&v12)[9],
        f32x2 (&a0p)[4], float& a0s, f32x2 (&a12)[9]) {
    const float* rb = mbase + QS*720 + q*20;
#pragma unroll
    for (int kc = 0; kc < 9; ++kc) {
        float b0 = qb<QS>(v0[kc]);
        f32x2 b12; b12.x = qb<QS>(v12[kc].x); b12.y = qb<QS>(v12[kc].y);
        f32x2 bb0 = {b0, b0};
        const float4* rp = (const float4*)(rb + kc*80);
        float4 R0 = rp[0], R1 = rp[1], R2 = rp[2], R3 = rp[3], R4 = rp[4];
        f32x2 m0p[4] = {{R0.x,R0.y},{R0.z,R0.w},{R1.x,R1.y},{R1.z,R1.w}};
        float mA[9] = {R2.z,R2.w,R3.x,R3.y,R3.z,R3.w,R4.x,R4.y,R4.z};
#pragma unroll
        for (int k = 0; k < 4; ++k) a0p[k] = m0p[k] * bb0 + a0p[k];
        a0s = fmaf(R2.x, b0, a0s);
#pragma unroll
        for (int k = 0; k < 9; ++k) {
            f32x2 mm = {mA[k], mA[k]};
            a12[k] = mm * b12 + a12[k];
        }
    }
}

// ---------------- precompute reduced matrices (+ zero deg) ----------------
__global__ void precompute_kernel(const float* __restrict__ K2N,
                                  const float* __restrict__ K2E,
                                  const float* __restrict__ KE1,
                                  const float* __restrict__ KE2,
                                  const float* __restrict__ KNc,
                                  float* __restrict__ ws,
                                  int* __restrict__ deg) {
    int tid = blockIdx.x * blockDim.x + threadIdx.x;
    int nthr = gridDim.x * blockDim.x;
    if (tid < N_NODES) deg[tid] = 0;
    for (int m = tid; m < 1440; m += nthr) {
        ws[MIT_OFF + m*20 + 9]  = 0.f;
        ws[MIT_OFF + m*20 + 19] = 0.f;
    }
    for (int m = tid; m < 5*1296; m += nthr) {
        int l = m / 1296, oc = m % 1296;
        int o = oc / 36, c = oc % 36;
        int qq = o / 9, k = o % 9;
        const float* p1 = KE1 + (size_t)(l*1296 + oc)*6;
        const float* p2 = KE2 + (size_t)(l*1296 + oc)*6;
        int base = MIT_OFF + l*5760 + (c*4 + qq)*20;
        ws[base + k]             = p1[0] + p1[1] + p1[2];
        ws[base + 10 + k]        = p1[3] + p1[4] + p1[5];
        ws[base + 2880 + k]      = p2[0] + p2[1] + p2[2];
        ws[base + 2880 + 10 + k] = p2[3] + p2[4] + p2[5];
    }
    for (int m = tid; m < 2*256; m += nthr) {
        int s = m / 256, oc = m % 256;
        const float* p = K2N + oc*6 + 3*s;
        ws[K2N_OFF + m] = p[0] + p[1] + p[2];
    }
    for (int m = tid; m < 2*54; m += nthr) {
        int s = m / 54, oc = m % 54;
        const float* p = KNc + oc*6 + 3*s;
        ws[KNC_OFF + m] = p[0] + p[1] + p[2];
    }
    if (tid < 2) {
        const float* p = K2E + 3*tid;
        ws[K2E_OFF + tid] = p[0] + p[1] + p[2];
    }
}

// ---------------- CSR build ----------------
__global__ void count_kernel(const int* __restrict__ iInd, const int* __restrict__ jInd,
                             int* __restrict__ deg) {
    int e = blockIdx.x * blockDim.x + threadIdx.x;
    if (e >= N_EDGES) return;
    atomicAdd(&deg[iInd[e]], 1);
    atomicAdd(&deg[jInd[e]], 1);
}

__global__ void scan_kernel(const int* __restrict__ deg, int* __restrict__ rowptr,
                            int* __restrict__ fpos) {
    __shared__ int lds[256];
    int t = threadIdx.x;
    int base = t * 32;
    int s = 0;
#pragma unroll
    for (int k = 0; k < 32; ++k) s += deg[base + k];
    lds[t] = s;
    __syncthreads();
    if (t == 0) {
        int run = 0;
        for (int k = 0; k < 256; ++k) { int v = lds[k]; lds[k] = run; run += v; }
        rowptr[N_NODES] = run;
    }
    __syncthreads();
    int off = lds[t];
#pragma unroll
    for (int k = 0; k < 32; ++k) {
        rowptr[base + k] = off;
        fpos[base + k] = off;
        off += deg[base + k];
    }
}

__global__ void fill_kernel(const int* __restrict__ iInd, const int* __restrict__ jInd,
                            int* __restrict__ fpos,
                            int* __restrict__ posI, int* __restrict__ posJ) {
    int e = blockIdx.x * blockDim.x + threadIdx.x;
    if (e >= N_EDGES) return;
    posI[e] = atomicAdd(&fpos[iInd[e]], 1);
    posJ[e] = atomicAdd(&fpos[jInd[e]], 1);
}

// ---------------- opening: node (blocks 0..31) + edge (blocks 32..287) ----------------
__global__ void open_kernel(const float* __restrict__ xnV,
                            const float* __restrict__ xeV,
                            const float* __restrict__ Q,
                            const float* __restrict__ K1N,
                            const float* __restrict__ K1E,
                            const float* __restrict__ ws,
                            const int* __restrict__ posI, const int* __restrict__ posJ,
                            float* __restrict__ xn3,
                            float4* __restrict__ seslot) {
    float q0 = Q[0], q1 = Q[1], q2 = Q[2];
    float iq2 = 1.f / (q0*q0 + q1*q1 + q2*q2);

    if (blockIdx.x < 32) {
        int n = blockIdx.x * 256 + threadIdx.x;
        float R[3][9];
#pragma unroll
        for (int c = 0; c < 3; ++c)
#pragma unroll
            for (int p = 0; p < 9; ++p)
                R[c][p] = xnV[(c*9 + p)*N_NODES + n];
#pragma unroll
        for (int c = 0; c < 3; ++c)
#pragma unroll
            for (int v = 0; v < 3; ++v)
                vrelu3(R[c][3*v], R[c][3*v+1], R[c][3*v+2], q0, q1, q2, iq2);

        float s[16][3];
#pragma unroll
        for (int o = 0; o < 16; ++o) {
            float a0 = 0.f, a1 = 0.f, a2 = 0.f;
#pragma unroll
            for (int c = 0; c < 3; ++c)
#pragma unroll
                for (int g = 0; g < 3; ++g) {
                    a0 = fmaf(R[c][3*g + 0], K1N[(o*3 + c)*6 + g],     a0);
                    a1 = fmaf(R[c][3*g + 1], K1N[(o*3 + c)*6 + 3 + g], a1);
                    a2 = fmaf(R[c][3*g + 2], K1N[(o*3 + c)*6 + 3 + g], a2);
                }
            s[o][0] = a0; s[o][1] = a1; s[o][2] = a2;
        }
#pragma unroll
        for (int o = 0; o < 16; ++o)
            vrelu3(s[o][0], s[o][1], s[o][2], q0, q1, q2, iq2);

        float u[16][3];
#pragma unroll
        for (int o = 0; o < 16; ++o) {
            float a0 = 0.f, a1 = 0.f, a2 = 0.f;
#pragma unroll
            for (int c = 0; c < 16; ++c) {
                float m0 = ws[K2N_OFF + o*16 + c];
                float mA = ws[K2N_OFF + 256 + o*16 + c];
                a0 = fmaf(m0, s[c][0], a0);
                a1 = fmaf(mA, s[c][1], a1);
                a2 = fmaf(mA, s[c][2], a2);
            }
            u[o][0] = a0; u[o][1] = a1; u[o][2] = a2;
            vrelu3(u[o][0], u[o][1], u[o][2], q0, q1, q2, iq2);
        }

        float* dst = xn3 + n*NS;
#pragma unroll
        for (int o = 0; o < 16; ++o) {
            int base = (o/9)*28 + (o%9)*3;
#pragma unroll
            for (int g = 0; g < 3; ++g)
                dst[base + g] = u[o][g];
        }
        dst[27] = 0.f;
    } else {
        int e = (blockIdx.x - 32) * 256 + threadIdx.x;
        float R[9];
#pragma unroll
        for (int p = 0; p < 9; ++p) R[p] = xeV[p*N_EDGES + e];
#pragma unroll
        for (int v = 0; v < 3; ++v)
            vrelu3(R[3*v], R[3*v+1], R[3*v+2], q0, q1, q2, iq2);

        float s0 = 0.f, s1 = 0.f, s2 = 0.f;
#pragma unroll
        for (int g = 0; g < 3; ++g) {
            s0 = fmaf(R[3*g + 0], K1E[g],     s0);
            s1 = fmaf(R[3*g + 1], K1E[3 + g], s1);
            s2 = fmaf(R[3*g + 2], K1E[3 + g], s2);
        }
        vrelu3(s0, s1, s2, q0, q1, q2, iq2);
        s0 *= ws[K2E_OFF + 0];
        s1 *= ws[K2E_OFF + 1];
        s2 *= ws[K2E_OFF + 1];
        vrelu3(s0, s1, s2, q0, q1, q2, iq2);

        int pi = posI[e], pj = posJ[e];
        // i-slot: div +s, ave +0.5s ; j-slot: div -s, ave +0.5s
        seslot[2*pi]     = make_float4(s0, s1, s2, 0.f);
        seslot[2*pi + 1] = make_float4(0.5f*s0, 0.5f*s1, 0.5f*s2, 0.f);
        seslot[2*pj]     = make_float4(-s0, -s1, -s2, 0.f);
        seslot[2*pj + 1] = make_float4(0.5f*s0, 0.5f*s1, 0.5f*s2, 0.f);
    }
}

// gather edge-open contributions into xn3 channels 16,17 — streaming CSR reads
__global__ void open_gather_kernel(const float4* __restrict__ seslot,
                                   const int* __restrict__ rowptr,
                                   float* __restrict__ xn3) {
    int n = blockIdx.x * blockDim.x + threadIdx.x;
    if (n >= N_NODES) return;
    int beg = rowptr[n], end = rowptr[n + 1];
    float d0 = 0.f, d1 = 0.f, d2 = 0.f, a0 = 0.f, a1 = 0.f, a2 = 0.f;
    for (int d = beg; d < end; ++d) {
        float4 dv = seslot[2*d];
        float4 av = seslot[2*d + 1];
        d0 += dv.x; d1 += dv.y; d2 += dv.z;
        a0 += av.x; a1 += av.y; a2 += av.z;
    }
    float* dst = xn3 + n*NS;
    dst[49] = d0; dst[50] = d1; dst[51] = d2;
    dst[52] = a0; dst[53] = a1; dst[54] = a2;
    dst[55] = 0.f;
}

// ---------------- per-layer phase A: 4 threads/edge, DPP broadcast, CSR-slot output ----------------
template<bool WRITE_FLUX>
__global__ __launch_bounds__(256, 4) void edge_compute_kernel(
        const float* __restrict__ xn3,
        const int* __restrict__ iInd, const int* __restrict__ jInd,
        const int* __restrict__ posI, const int* __restrict__ posJ,
        const float* __restrict__ Q,
        const float* __restrict__ mitg,   // [2][36][4][20]
        float* __restrict__ flux, float* __restrict__ fluxOut) {
    __shared__ float mit[5760];
    {
        const float4* s4 = (const float4*)mitg;
        float4* d4 = (float4*)mit;
        for (int t = threadIdx.x; t < 1440; t += 256) d4[t] = s4[t];
    }
    __syncthreads();

    int tid = blockIdx.x * 256 + threadIdx.x;
    int e = tid >> 2, q = tid & 3;
    float q0 = Q[0];
    f32x2 q12 = {Q[1], Q[2]};
    float iq2 = 1.f / (q0*q0 + q12.x*q12.x + q12.y*q12.y);
    int i = iInd[e], j = jInd[e];
    const float4* xi = (const float4*)(xn3 + i*NS + 28*(q & 1));
    const float4* xj = (const float4*)(xn3 + j*NS + 28*(q & 1));

    float A[28], B[28];
    ld28(xi, A);
    ld28(xj, B);

    bool isAve = q >= 2;
    float sA = isAve ? 0.5f :  1.f;
    float sB = isAve ? 0.5f : -1.f;
    float v0[9]; f32x2 v12[9];
#pragma unroll
    for (int k = 0; k < 9; ++k) {
        v0[k]    = fmaf(sA, A[3*k],   sB * B[3*k]);
        v12[k].x = fmaf(sA, A[3*k+1], sB * B[3*k+1]);
        v12[k].y = fmaf(sA, A[3*k+2], sB * B[3*k+2]);
        vrelu_p(v0[k], v12[k], q0, q12, iq2);
    }

    f32x2 a0p[4]; float a0s; f32x2 a12[9];
#pragma unroll
    for (int k = 0; k < 4; ++k) a0p[k] = (f32x2){0.f, 0.f};
    a0s = 0.f;
#pragma unroll
    for (int k = 0; k < 9; ++k) a12[k] = (f32x2){0.f, 0.f};
    matvec_part<0>(mit, q, v0, v12, a0p, a0s, a12);
    matvec_part<1>(mit, q, v0, v12, a0p, a0s, a12);
    matvec_part<2>(mit, q, v0, v12, a0p, a0s, a12);
    matvec_part<3>(mit, q, v0, v12, a0p, a0s, a12);
    // unpack, relu, repack as next-stage input
#pragma unroll
    for (int k = 0; k < 9; ++k) {
        float w0 = (k < 8) ? ((k & 1) ? a0p[k>>1].y : a0p[k>>1].x) : a0s;
        f32x2 w12 = a12[k];
        vrelu_p(w0, w12, q0, q12, iq2);
        v0[k] = w0; v12[k] = w12;
    }
#pragma unroll
    for (int k = 0; k < 4; ++k) a0p[k] = (f32x2){0.f, 0.f};
    a0s = 0.f;
#pragma unroll
    for (int k = 0; k < 9; ++k) a12[k] = (f32x2){0.f, 0.f};
    matvec_part<0>(mit + 2880, q, v0, v12, a0p, a0s, a12);
    matvec_part<1>(mit + 2880, q, v0, v12, a0p, a0s, a12);
    matvec_part<2>(mit + 2880, q, v0, v12, a0p, a0s, a12);
    matvec_part<3>(mit + 2880, q, v0, v12, a0p, a0s, a12);

    float w0[9]; f32x2 w12[9];
#pragma unroll
    for (int k = 0; k < 9; ++k) {
        w0[k] = (k < 8) ? ((k & 1) ? a0p[k>>1].y : a0p[k>>1].x) : a0s;
        w12[k] = a12[k];
        vrelu_p(w0[k], w12[k], q0, q12, iq2);
    }

    // pp (q<2): own(div) + 0.5*partner(ave);  pm (q>=2): 0.5*own(ave) - partner(div)
    float selO = (q < 2) ? 1.f  : 0.5f;
    float selP = (q < 2) ? 0.5f : -1.f;
    float outv[28];
#pragma unroll
    for (int k = 0; k < 9; ++k) {
        float o0 = qswap2(w0[k]);
        float o1 = qswap2(w12[k].x);
        float o2 = qswap2(w12[k].y);
        outv[3*k]   = fmaf(selO, w0[k],    selP * o0);
        outv[3*k+1] = fmaf(selO, w12[k].x, selP * o1);
        outv[3*k+2] = fmaf(selO, w12[k].y, selP * o2);
    }
    outv[27] = 0.f;
    int slot = (q < 2) ? posI[e] : posJ[e];
    float4* frow = (float4*)(flux + (size_t)slot*56 + (q & 1)*28);
#pragma unroll
    for (int t = 0; t < 7; ++t)
        frow[t] = make_float4(outv[4*t], outv[4*t+1], outv[4*t+2], outv[4*t+3]);

    if (WRITE_FLUX) {
#pragma unroll
        for (int k = 0; k < 9; ++k) {
#pragma unroll
            for (int p = 0; p < 9; ++p) {
                float wv = (p % 3 == 0) ? w0[k] : (p % 3 == 1) ? w12[k].x : w12[k].y;
                fluxOut[((size_t)((9*q + k)*9 + p))*N_EDGES + e] = wv;
            }
        }
    }
}

// ---------------- per-layer phase B: wave-per-node STREAMING gather + xn update ----------------
__global__ __launch_bounds__(64) void node_gather_kernel(
        const float* __restrict__ flux,
        const int* __restrict__ rowptr,
        float* __restrict__ xn3) {
    int n = blockIdx.x;
    int l = threadIdx.x;
    if (l >= 56) return;
    int beg = rowptr[n], end = rowptr[n + 1];
    const float* p = flux + (size_t)beg * 56 + l;
    float acc = 0.f, acc2 = 0.f;
    int d = beg;
    for (; d + 2 <= end; d += 2) {
        acc  += p[0];
        acc2 += p[56];
        p += 112;
    }
    if (d < end) acc += p[0];
    acc += acc2;
    float* x = xn3 + n*NS + l;
    *x = fmaf(-0.1f, acc, *x);
}

// ---------------- closing layer ----------------
__global__ void close_kernel(const float* __restrict__ xn3,
                             const float* __restrict__ ws,
                             float* __restrict__ out) {
    int n = blockIdx.x * blockDim.x + threadIdx.x;
    if (n >= N_NODES) return;
    const float* x = xn3 + n*NS;
    float o[3][3];
#pragma unroll
    for (int oo = 0; oo < 3; ++oo) {
        float a0 = 0.f, a1 = 0.f, a2 = 0.f;
#pragma unroll
        for (int c = 0; c < 18; ++c) {
            int xidx = (c/9)*28 + (c%9)*3;
            float m0 = ws[KNC_OFF + oo*18 + c];
            float mA = ws[KNC_OFF + 54 + oo*18 + c];
            a0 = fmaf(m0, x[xidx + 0], a0);
            a1 = fmaf(mA, x[xidx + 1], a1);
            a2 = fmaf(mA, x[xidx + 2], a2);
        }
        o[oo][0] = a0; o[oo][1] = a1; o[oo][2] = a2;
    }
#pragma unroll
    for (int oo = 0; oo < 3; ++oo)
#pragma unroll
        for (int p = 0; p < 9; ++p)
            out[(oo*9 + p)*N_NODES + n] = o[oo][p % 3];
}

extern "C" void kernel_launch(void* const* d_in, const int* in_sizes, int n_in,
                              void* d_out, int out_size, void* d_ws, size_t ws_size,
                              hipStream_t stream) {
    const float* xnV = (const float*)d_in[0];
    const float* xeV = (const float*)d_in[1];
    const int*   iInd = (const int*)d_in[2];
    const int*   jInd = (const int*)d_in[3];
    const float* K1N = (const float*)d_in[4];
    const float* K2N = (const float*)d_in[5];
    const float* K1E = (const float*)d_in[6];
    const float* K2E = (const float*)d_in[7];
    const float* KE1 = (const float*)d_in[8];
    const float* KE2 = (const float*)d_in[9];
    const float* KNc = (const float*)d_in[10];
    const float* Q   = (const float*)d_in[11];

    float* ws   = (float*)d_ws;
    float* xn3  = ws + XN3_OFF;
    float* flux = ws + FLUX_OFF;
    int* wsi    = (int*)d_ws;
    int* deg    = wsi + DEG_OFF;
    int* rowptr = wsi + RP_OFF;
    int* fpos   = wsi + FP_OFF;
    int* posI   = wsi + POSI_OFF;
    int* posJ   = wsi + POSJ_OFF;

    float* out  = (float*)d_out;
    float* fluxOut = out + 3*9*N_NODES;

    precompute_kernel<<<64, 256, 0, stream>>>(K2N, K2E, KE1, KE2, KNc, ws, deg);
    count_kernel<<<N_EDGES/256, 256, 0, stream>>>(iInd, jInd, deg);
    scan_kernel<<<1, 256, 0, stream>>>(deg, rowptr, fpos);
    fill_kernel<<<N_EDGES/256, 256, 0, stream>>>(iInd, jInd, fpos, posI, posJ);

    open_kernel<<<32 + N_EDGES/256, 256, 0, stream>>>(
        xnV, xeV, Q, K1N, K1E, ws, posI, posJ, xn3, (float4*)flux);
    open_gather_kernel<<<N_NODES/256, 256, 0, stream>>>((const float4*)flux, rowptr, xn3);

    for (int l = 0; l < 5; ++l) {
        const float* mitg = ws + MIT_OFF + l*5760;
        if (l == 4)
            edge_compute_kernel<true><<<N_EDGES*4/256, 256, 0, stream>>>(
                xn3, iInd, jInd, posI, posJ, Q, mitg, flux, fluxOut);
        else
            edge_compute_kernel<false><<<N_EDGES*4/256, 256, 0, stream>>>(
                xn3, iInd, jInd, posI, posJ, Q, mitg, flux, nullptr);
        node_gather_kernel<<<N_NODES, 64, 0, stream>>>(flux, rowptr, xn3);
    }

    close_kernel<<<N_NODES/256, 256, 0, stream>>>(xn3, ws, out);
}

// Round 7
// 281.915 us; speedup vs baseline: 7.6778x; 1.0901x over previous
//
#include <hip/hip_runtime.h>

// Problem constants (fixed by setup_inputs)
#define N_NODES 8192
#define N_EDGES 65536
#define NS 56    // node state: 2 halves of 28 floats (27 used + pad); ch c class g at (c/9)*28+(c%9)*3+g
// flux16: CSR-slot layout [2E slots][64 halves] — one 128B cache line per endpoint contribution.
//   half l (l<32: half0=ch 0..8, l>=32: half1=ch 9..17), within half: 3k+g order, 27 used + 5 pad.

// Workspace layout (word offsets into d_ws)
#define XN3_OFF   0                                   // [8192][56] floats
#define MIT_OFF   (N_NODES*NS)                        // [5][2 stages][36 c][4 q][20] floats
#define K2N_OFF   (MIT_OFF + 5*5760)                  // [2][16][16]
#define KNC_OFF   (K2N_OFF + 2*16*16)                 // [2][3][18]
#define K2E_OFF   (KNC_OFF + 2*3*18)                  // [2]
#define FLUX_OFF  488176                              // 16B-aligned; [2E][32] u32 (fp16 pairs)
#define FLUX_END  (FLUX_OFF + 2*N_EDGES*32)
#define DEG_OFF   FLUX_END
#define RP_OFF    (DEG_OFF + N_NODES)
#define FP_OFF    (RP_OFF + N_NODES + 1)
#define POSI_OFF  (FP_OFF + N_NODES)
#define POSJ_OFF  (POSI_OFF + N_EDGES)

typedef float f32x2 __attribute__((ext_vector_type(2)));
typedef __fp16 fp16x2 __attribute__((ext_vector_type(2)));

__device__ __forceinline__ unsigned pkrtz(float a, float b) {
    fp16x2 h = __builtin_amdgcn_cvt_pkrtz(a, b);
    return *(unsigned*)&h;
}

// quad-perm broadcast of slot SLOT within each aligned 4-lane group (VALU DPP, no LDS)
template<int SLOT>
__device__ __forceinline__ float qb(float x) {
    int r = __builtin_amdgcn_update_dpp(0, __float_as_int(x), SLOT * 0x55, 0xf, 0xf, true);
    return __int_as_float(r);
}
// quad-perm [2,3,0,1]: exchange lanes q <-> q^2
__device__ __forceinline__ float qswap2(float x) {
    int r = __builtin_amdgcn_update_dpp(0, __float_as_int(x), 0x4E, 0xf, 0xf, true);
    return __int_as_float(r);
}

__device__ __forceinline__ void vrelu_p(float& a0, f32x2& a12,
                                        float q0, f32x2 q12, float iq2) {
    float t = fmaf(a0, q0, fmaf(a12.x, q12.x, a12.y * q12.y));
    float r = t > 0.f ? t * iq2 : 0.f;
    a0 = fmaf(-r, q0, a0);
    f32x2 nr = {-r, -r};
    a12 = nr * q12 + a12;
}

__device__ __forceinline__ void vrelu3(float& x0, float& x1, float& x2,
                                       float q0, float q1, float q2, float iq2) {
    float t = x0*q0 + x1*q1 + x2*q2;
    float r = t > 0.f ? t*iq2 : 0.f;
    x0 = fmaf(-r, q0, x0);
    x1 = fmaf(-r, q1, x1);
    x2 = fmaf(-r, q2, x2);
}

__device__ __forceinline__ void ld28(const float4* __restrict__ p, float (&d)[28]) {
#pragma unroll
    for (int t = 0; t < 7; ++t) {
        float4 r = p[t];
        d[4*t] = r.x; d[4*t+1] = r.y; d[4*t+2] = r.z; d[4*t+3] = r.w;
    }
}

// one quarter of the 36-channel matvec: input channels [QS*9, QS*9+9) broadcast
// from quad slot QS; this thread accumulates its own 9 output channels.
// class 0 accumulators packed as 4x f32x2 + 1 scalar (v_pk_fma_f32).
template<int QS>
__device__ __forceinline__ void matvec_part(const float* __restrict__ mbase, int q,
        const float (&v0)[9], const f32x2 (&v12)[9],
        f32x2 (&a0p)[4], float& a0s, f32x2 (&a12)[9]) {
    const float* rb = mbase + QS*720 + q*20;
#pragma unroll
    for (int kc = 0; kc < 9; ++kc) {
        float b0 = qb<QS>(v0[kc]);
        f32x2 b12; b12.x = qb<QS>(v12[kc].x); b12.y = qb<QS>(v12[kc].y);
        f32x2 bb0 = {b0, b0};
        const float4* rp = (const float4*)(rb + kc*80);
        float4 R0 = rp[0], R1 = rp[1], R2 = rp[2], R3 = rp[3], R4 = rp[4];
        f32x2 m0p[4] = {{R0.x,R0.y},{R0.z,R0.w},{R1.x,R1.y},{R1.z,R1.w}};
        float mA[9] = {R2.z,R2.w,R3.x,R3.y,R3.z,R3.w,R4.x,R4.y,R4.z};
#pragma unroll
        for (int k = 0; k < 4; ++k) a0p[k] = m0p[k] * bb0 + a0p[k];
        a0s = fmaf(R2.x, b0, a0s);
#pragma unroll
        for (int k = 0; k < 9; ++k) {
            f32x2 mm = {mA[k], mA[k]};
            a12[k] = mm * b12 + a12[k];
        }
    }
}

// ---------------- precompute reduced matrices (+ zero deg) ----------------
__global__ void precompute_kernel(const float* __restrict__ K2N,
                                  const float* __restrict__ K2E,
                                  const float* __restrict__ KE1,
                                  const float* __restrict__ KE2,
                                  const float* __restrict__ KNc,
                                  float* __restrict__ ws,
                                  int* __restrict__ deg) {
    int tid = blockIdx.x * blockDim.x + threadIdx.x;
    int nthr = gridDim.x * blockDim.x;
    if (tid < N_NODES) deg[tid] = 0;
    for (int m = tid; m < 1440; m += nthr) {
        ws[MIT_OFF + m*20 + 9]  = 0.f;
        ws[MIT_OFF + m*20 + 19] = 0.f;
    }
    for (int m = tid; m < 5*1296; m += nthr) {
        int l = m / 1296, oc = m % 1296;
        int o = oc / 36, c = oc % 36;
        int qq = o / 9, k = o % 9;
        const float* p1 = KE1 + (size_t)(l*1296 + oc)*6;
        const float* p2 = KE2 + (size_t)(l*1296 + oc)*6;
        int base = MIT_OFF + l*5760 + (c*4 + qq)*20;
        ws[base + k]             = p1[0] + p1[1] + p1[2];
        ws[base + 10 + k]        = p1[3] + p1[4] + p1[5];
        ws[base + 2880 + k]      = p2[0] + p2[1] + p2[2];
        ws[base + 2880 + 10 + k] = p2[3] + p2[4] + p2[5];
    }
    for (int m = tid; m < 2*256; m += nthr) {
        int s = m / 256, oc = m % 256;
        const float* p = K2N + oc*6 + 3*s;
        ws[K2N_OFF + m] = p[0] + p[1] + p[2];
    }
    for (int m = tid; m < 2*54; m += nthr) {
        int s = m / 54, oc = m % 54;
        const float* p = KNc + oc*6 + 3*s;
        ws[KNC_OFF + m] = p[0] + p[1] + p[2];
    }
    if (tid < 2) {
        const float* p = K2E + 3*tid;
        ws[K2E_OFF + tid] = p[0] + p[1] + p[2];
    }
}

// ---------------- CSR build ----------------
__global__ void count_kernel(const int* __restrict__ iInd, const int* __restrict__ jInd,
                             int* __restrict__ deg) {
    int e = blockIdx.x * blockDim.x + threadIdx.x;
    if (e >= N_EDGES) return;
    atomicAdd(&deg[iInd[e]], 1);
    atomicAdd(&deg[jInd[e]], 1);
}

__global__ void scan_kernel(const int* __restrict__ deg, int* __restrict__ rowptr,
                            int* __restrict__ fpos) {
    __shared__ int lds[256];
    int t = threadIdx.x;
    int base = t * 32;
    int s = 0;
#pragma unroll
    for (int k = 0; k < 32; ++k) s += deg[base + k];
    lds[t] = s;
    __syncthreads();
    if (t == 0) {
        int run = 0;
        for (int k = 0; k < 256; ++k) { int v = lds[k]; lds[k] = run; run += v; }
        rowptr[N_NODES] = run;
    }
    __syncthreads();
    int off = lds[t];
#pragma unroll
    for (int k = 0; k < 32; ++k) {
        rowptr[base + k] = off;
        fpos[base + k] = off;
        off += deg[base + k];
    }
}

__global__ void fill_kernel(const int* __restrict__ iInd, const int* __restrict__ jInd,
                            int* __restrict__ fpos,
                            int* __restrict__ posI, int* __restrict__ posJ) {
    int e = blockIdx.x * blockDim.x + threadIdx.x;
    if (e >= N_EDGES) return;
    posI[e] = atomicAdd(&fpos[iInd[e]], 1);
    posJ[e] = atomicAdd(&fpos[jInd[e]], 1);
}

// ---------------- opening: node (blocks 0..31) + edge (blocks 32..287) ----------------
__global__ void open_kernel(const float* __restrict__ xnV,
                            const float* __restrict__ xeV,
                            const float* __restrict__ Q,
                            const float* __restrict__ K1N,
                            const float* __restrict__ K1E,
                            const float* __restrict__ ws,
                            const int* __restrict__ posI, const int* __restrict__ posJ,
                            float* __restrict__ xn3,
                            float4* __restrict__ seslot) {
    float q0 = Q[0], q1 = Q[1], q2 = Q[2];
    float iq2 = 1.f / (q0*q0 + q1*q1 + q2*q2);

    if (blockIdx.x < 32) {
        int n = blockIdx.x * 256 + threadIdx.x;
        float R[3][9];
#pragma unroll
        for (int c = 0; c < 3; ++c)
#pragma unroll
            for (int p = 0; p < 9; ++p)
                R[c][p] = xnV[(c*9 + p)*N_NODES + n];
#pragma unroll
        for (int c = 0; c < 3; ++c)
#pragma unroll
            for (int v = 0; v < 3; ++v)
                vrelu3(R[c][3*v], R[c][3*v+1], R[c][3*v+2], q0, q1, q2, iq2);

        float s[16][3];
#pragma unroll
        for (int o = 0; o < 16; ++o) {
            float a0 = 0.f, a1 = 0.f, a2 = 0.f;
#pragma unroll
            for (int c = 0; c < 3; ++c)
#pragma unroll
                for (int g = 0; g < 3; ++g) {
                    a0 = fmaf(R[c][3*g + 0], K1N[(o*3 + c)*6 + g],     a0);
                    a1 = fmaf(R[c][3*g + 1], K1N[(o*3 + c)*6 + 3 + g], a1);
                    a2 = fmaf(R[c][3*g + 2], K1N[(o*3 + c)*6 + 3 + g], a2);
                }
            s[o][0] = a0; s[o][1] = a1; s[o][2] = a2;
        }
#pragma unroll
        for (int o = 0; o < 16; ++o)
            vrelu3(s[o][0], s[o][1], s[o][2], q0, q1, q2, iq2);

        float u[16][3];
#pragma unroll
        for (int o = 0; o < 16; ++o) {
            float a0 = 0.f, a1 = 0.f, a2 = 0.f;
#pragma unroll
            for (int c = 0; c < 16; ++c) {
                float m0 = ws[K2N_OFF + o*16 + c];
                float mA = ws[K2N_OFF + 256 + o*16 + c];
                a0 = fmaf(m0, s[c][0], a0);
                a1 = fmaf(mA, s[c][1], a1);
                a2 = fmaf(mA, s[c][2], a2);
            }
            u[o][0] = a0; u[o][1] = a1; u[o][2] = a2;
            vrelu3(u[o][0], u[o][1], u[o][2], q0, q1, q2, iq2);
        }

        float* dst = xn3 + n*NS;
#pragma unroll
        for (int o = 0; o < 16; ++o) {
            int base = (o/9)*28 + (o%9)*3;
#pragma unroll
            for (int g = 0; g < 3; ++g)
                dst[base + g] = u[o][g];
        }
        dst[27] = 0.f;
    } else {
        int e = (blockIdx.x - 32) * 256 + threadIdx.x;
        float R[9];
#pragma unroll
        for (int p = 0; p < 9; ++p) R[p] = xeV[p*N_EDGES + e];
#pragma unroll
        for (int v = 0; v < 3; ++v)
            vrelu3(R[3*v], R[3*v+1], R[3*v+2], q0, q1, q2, iq2);

        float s0 = 0.f, s1 = 0.f, s2 = 0.f;
#pragma unroll
        for (int g = 0; g < 3; ++g) {
            s0 = fmaf(R[3*g + 0], K1E[g],     s0);
            s1 = fmaf(R[3*g + 1], K1E[3 + g], s1);
            s2 = fmaf(R[3*g + 2], K1E[3 + g], s2);
        }
        vrelu3(s0, s1, s2, q0, q1, q2, iq2);
        s0 *= ws[K2E_OFF + 0];
        s1 *= ws[K2E_OFF + 1];
        s2 *= ws[K2E_OFF + 1];
        vrelu3(s0, s1, s2, q0, q1, q2, iq2);

        // slot stores div contribution + sign (ave = 0.5*sign*div)
        seslot[posI[e]] = make_float4( s0,  s1,  s2,  1.f);
        seslot[posJ[e]] = make_float4(-s0, -s1, -s2, -1.f);
    }
}

// gather edge-open contributions into xn3 channels 16,17 — streaming CSR reads
__global__ void open_gather_kernel(const float4* __restrict__ seslot,
                                   const int* __restrict__ rowptr,
                                   float* __restrict__ xn3) {
    int n = blockIdx.x * blockDim.x + threadIdx.x;
    if (n >= N_NODES) return;
    int beg = rowptr[n], end = rowptr[n + 1];
    float d0 = 0.f, d1 = 0.f, d2 = 0.f, a0 = 0.f, a1 = 0.f, a2 = 0.f;
    for (int d = beg; d < end; ++d) {
        float4 v = seslot[d];
        d0 += v.x; d1 += v.y; d2 += v.z;
        float hs = 0.5f * v.w;
        a0 = fmaf(hs, v.x, a0); a1 = fmaf(hs, v.y, a1); a2 = fmaf(hs, v.z, a2);
    }
    float* dst = xn3 + n*NS;
    // ch16 -> half1 idx 49..51, ch17 -> 52..54, pad 55
    dst[49] = d0; dst[50] = d1; dst[51] = d2;
    dst[52] = a0; dst[53] = a1; dst[54] = a2;
    dst[55] = 0.f;
}

// ---------------- per-layer phase A: 4 threads/edge, fp16 line-exact CSR-slot output ----------------
template<bool WRITE_FLUX>
__global__ __launch_bounds__(256, 4) void edge_compute_kernel(
        const float* __restrict__ xn3,
        const int* __restrict__ iInd, const int* __restrict__ jInd,
        const int* __restrict__ posI, const int* __restrict__ posJ,
        const float* __restrict__ Q,
        const float* __restrict__ mitg,   // [2][36][4][20]
        unsigned* __restrict__ flux16, float* __restrict__ fluxOut) {
    __shared__ float mit[5760];
    {
        const float4* s4 = (const float4*)mitg;
        float4* d4 = (float4*)mit;
        for (int t = threadIdx.x; t < 1440; t += 256) d4[t] = s4[t];
    }
    __syncthreads();

    int tid = blockIdx.x * 256 + threadIdx.x;
    int e = tid >> 2, q = tid & 3;
    float q0 = Q[0];
    f32x2 q12 = {Q[1], Q[2]};
    float iq2 = 1.f / (q0*q0 + q12.x*q12.x + q12.y*q12.y);
    int i = iInd[e], j = jInd[e];
    const float4* xi = (const float4*)(xn3 + i*NS + 28*(q & 1));
    const float4* xj = (const float4*)(xn3 + j*NS + 28*(q & 1));

    float A[28], B[28];
    ld28(xi, A);
    ld28(xj, B);

    bool isAve = q >= 2;
    float sA = isAve ? 0.5f :  1.f;
    float sB = isAve ? 0.5f : -1.f;
    float v0[9]; f32x2 v12[9];
#pragma unroll
    for (int k = 0; k < 9; ++k) {
        v0[k]    = fmaf(sA, A[3*k],   sB * B[3*k]);
        v12[k].x = fmaf(sA, A[3*k+1], sB * B[3*k+1]);
        v12[k].y = fmaf(sA, A[3*k+2], sB * B[3*k+2]);
        vrelu_p(v0[k], v12[k], q0, q12, iq2);
    }

    f32x2 a0p[4]; float a0s; f32x2 a12[9];
#pragma unroll
    for (int k = 0; k < 4; ++k) a0p[k] = (f32x2){0.f, 0.f};
    a0s = 0.f;
#pragma unroll
    for (int k = 0; k < 9; ++k) a12[k] = (f32x2){0.f, 0.f};
    matvec_part<0>(mit, q, v0, v12, a0p, a0s, a12);
    matvec_part<1>(mit, q, v0, v12, a0p, a0s, a12);
    matvec_part<2>(mit, q, v0, v12, a0p, a0s, a12);
    matvec_part<3>(mit, q, v0, v12, a0p, a0s, a12);
#pragma unroll
    for (int k = 0; k < 9; ++k) {
        float w0 = (k < 8) ? ((k & 1) ? a0p[k>>1].y : a0p[k>>1].x) : a0s;
        f32x2 w12 = a12[k];
        vrelu_p(w0, w12, q0, q12, iq2);
        v0[k] = w0; v12[k] = w12;
    }
#pragma unroll
    for (int k = 0; k < 4; ++k) a0p[k] = (f32x2){0.f, 0.f};
    a0s = 0.f;
#pragma unroll
    for (int k = 0; k < 9; ++k) a12[k] = (f32x2){0.f, 0.f};
    matvec_part<0>(mit + 2880, q, v0, v12, a0p, a0s, a12);
    matvec_part<1>(mit + 2880, q, v0, v12, a0p, a0s, a12);
    matvec_part<2>(mit + 2880, q, v0, v12, a0p, a0s, a12);
    matvec_part<3>(mit + 2880, q, v0, v12, a0p, a0s, a12);

    float w0[9]; f32x2 w12[9];
#pragma unroll
    for (int k = 0; k < 9; ++k) {
        w0[k] = (k < 8) ? ((k & 1) ? a0p[k>>1].y : a0p[k>>1].x) : a0s;
        w12[k] = a12[k];
        vrelu_p(w0[k], w12[k], q0, q12, iq2);
    }

    // pp (q<2): own(div) + 0.5*partner(ave);  pm (q>=2): 0.5*own(ave) - partner(div)
    float selO = (q < 2) ? 1.f  : 0.5f;
    float selP = (q < 2) ? 0.5f : -1.f;
    float outv[27];
#pragma unroll
    for (int k = 0; k < 9; ++k) {
        float o0 = qswap2(w0[k]);
        float o1 = qswap2(w12[k].x);
        float o2 = qswap2(w12[k].y);
        outv[3*k]   = fmaf(selO, w0[k],    selP * o0);
        outv[3*k+1] = fmaf(selO, w12[k].x, selP * o1);
        outv[3*k+2] = fmaf(selO, w12[k].y, selP * o2);
    }
    // pack 27 floats -> 16 u32 of fp16 pairs; quad covers one full 128B line per slot
    unsigned pk[16];
#pragma unroll
    for (int t = 0; t < 13; ++t) pk[t] = pkrtz(outv[2*t], outv[2*t+1]);
    pk[13] = pkrtz(outv[26], 0.f);
    pk[14] = 0u; pk[15] = 0u;
    int slot = (q < 2) ? posI[e] : posJ[e];
    uint4* dst = (uint4*)(flux16 + (size_t)slot*32 + (q & 1)*16);
    dst[0] = make_uint4(pk[0],  pk[1],  pk[2],  pk[3]);
    dst[1] = make_uint4(pk[4],  pk[5],  pk[6],  pk[7]);
    dst[2] = make_uint4(pk[8],  pk[9],  pk[10], pk[11]);
    dst[3] = make_uint4(pk[12], pk[13], pk[14], pk[15]);

    if (WRITE_FLUX) {
#pragma unroll
        for (int k = 0; k < 9; ++k) {
#pragma unroll
            for (int p = 0; p < 9; ++p) {
                float wv = (p % 3 == 0) ? w0[k] : (p % 3 == 1) ? w12[k].x : w12[k].y;
                fluxOut[((size_t)((9*q + k)*9 + p))*N_EDGES + e] = wv;
            }
        }
    }
}

// ---------------- per-layer phase B: wave-per-node streaming fp16 gather + xn update ----------------
__global__ __launch_bounds__(64) void node_gather_kernel(
        const __fp16* __restrict__ flux16,
        const int* __restrict__ rowptr,
        float* __restrict__ xn3) {
    int n = blockIdx.x;
    int l = threadIdx.x;
    int beg = rowptr[n], end = rowptr[n + 1];
    const __fp16* p = flux16 + (size_t)beg * 64 + l;
    float acc = 0.f, acc2 = 0.f;
    int d = beg;
    for (; d + 2 <= end; d += 2) {
        acc  += (float)p[0];
        acc2 += (float)p[64];
        p += 128;
    }
    if (d < end) acc += (float)p[0];
    acc += acc2;
    int m = l & 31;
    if (m < 27) {
        float* x = xn3 + n*NS + (l >> 5)*28 + m;
        *x = fmaf(-0.1f, acc, *x);
    }
}

// ---------------- closing layer ----------------
__global__ void close_kernel(const float* __restrict__ xn3,
                             const float* __restrict__ ws,
                             float* __restrict__ out) {
    int n = blockIdx.x * blockDim.x + threadIdx.x;
    if (n >= N_NODES) return;
    const float* x = xn3 + n*NS;
    float o[3][3];
#pragma unroll
    for (int oo = 0; oo < 3; ++oo) {
        float a0 = 0.f, a1 = 0.f, a2 = 0.f;
#pragma unroll
        for (int c = 0; c < 18; ++c) {
            int xidx = (c/9)*28 + (c%9)*3;
            float m0 = ws[KNC_OFF + oo*18 + c];
            float mA = ws[KNC_OFF + 54 + oo*18 + c];
            a0 = fmaf(m0, x[xidx + 0], a0);
            a1 = fmaf(mA, x[xidx + 1], a1);
            a2 = fmaf(mA, x[xidx + 2], a2);
        }
        o[oo][0] = a0; o[oo][1] = a1; o[oo][2] = a2;
    }
#pragma unroll
    for (int oo = 0; oo < 3; ++oo)
#pragma unroll
        for (int p = 0; p < 9; ++p)
            out[(oo*9 + p)*N_NODES + n] = o[oo][p % 3];
}

extern "C" void kernel_launch(void* const* d_in, const int* in_sizes, int n_in,
                              void* d_out, int out_size, void* d_ws, size_t ws_size,
                              hipStream_t stream) {
    const float* xnV = (const float*)d_in[0];
    const float* xeV = (const float*)d_in[1];
    const int*   iInd = (const int*)d_in[2];
    const int*   jInd = (const int*)d_in[3];
    const float* K1N = (const float*)d_in[4];
    const float* K2N = (const float*)d_in[5];
    const float* K1E = (const float*)d_in[6];
    const float* K2E = (const float*)d_in[7];
    const float* KE1 = (const float*)d_in[8];
    const float* KE2 = (const float*)d_in[9];
    const float* KNc = (const float*)d_in[10];
    const float* Q   = (const float*)d_in[11];

    float* ws   = (float*)d_ws;
    float* xn3  = ws + XN3_OFF;
    unsigned* flux16 = (unsigned*)(ws + FLUX_OFF);
    float4* se4 = (float4*)(ws + FLUX_OFF);       // overlays flux region (used only pre-layers)
    int* wsi    = (int*)d_ws;
    int* deg    = wsi + DEG_OFF;
    int* rowptr = wsi + RP_OFF;
    int* fpos   = wsi + FP_OFF;
    int* posI   = wsi + POSI_OFF;
    int* posJ   = wsi + POSJ_OFF;

    float* out  = (float*)d_out;
    float* fluxOut = out + 3*9*N_NODES;

    precompute_kernel<<<64, 256, 0, stream>>>(K2N, K2E, KE1, KE2, KNc, ws, deg);
    count_kernel<<<N_EDGES/256, 256, 0, stream>>>(iInd, jInd, deg);
    scan_kernel<<<1, 256, 0, stream>>>(deg, rowptr, fpos);
    fill_kernel<<<N_EDGES/256, 256, 0, stream>>>(iInd, jInd, fpos, posI, posJ);

    open_kernel<<<32 + N_EDGES/256, 256, 0, stream>>>(
        xnV, xeV, Q, K1N, K1E, ws, posI, posJ, xn3, se4);
    open_gather_kernel<<<N_NODES/256, 256, 0, stream>>>(se4, rowptr, xn3);

    for (int l = 0; l < 5; ++l) {
        const float* mitg = ws + MIT_OFF + l*5760;
        if (l == 4)
            edge_compute_kernel<true><<<N_EDGES*4/256, 256, 0, stream>>>(
                xn3, iInd, jInd, posI, posJ, Q, mitg, flux16, fluxOut);
        else
            edge_compute_kernel<false><<<N_EDGES*4/256, 256, 0, stream>>>(
                xn3, iInd, jInd, posI, posJ, Q, mitg, flux16, nullptr);
        node_gather_kernel<<<N_NODES, 64, 0, stream>>>((const __fp16*)flux16, rowptr, xn3);
    }

    close_kernel<<<N_NODES/256, 256, 0, stream>>>(xn3, ws, out);
}

// Round 8
// 280.833 us; speedup vs baseline: 7.7074x; 1.0039x over previous
//
#include <hip/hip_runtime.h>

// Problem constants (fixed by setup_inputs)
#define N_NODES 8192
#define N_EDGES 65536
#define NS 56    // node state: 2 halves of 28 floats (27 used + pad); ch c class g at (c/9)*28+(c%9)*3+g
// flux16: CSR-slot layout [2E slots][64 halves] — one 128B cache line per endpoint contribution.

// Workspace layout (word offsets into d_ws)
#define XN3_OFF   0                                   // [8192][56] floats
#define MIT_OFF   (N_NODES*NS)                        // [5][2 stages][36 c][4 q][20] floats
#define K2N_OFF   (MIT_OFF + 5*5760)                  // [2][16][16]
#define KNC_OFF   (K2N_OFF + 2*16*16)                 // [2][3][18]
#define K2E_OFF   (KNC_OFF + 2*3*18)                  // [2]
#define FLUX_OFF  488176                              // 16B-aligned; [2E][32] u32 (fp16 pairs)
#define FLUX_END  (FLUX_OFF + 2*N_EDGES*32)
#define DEG_OFF   FLUX_END
#define RP_OFF    (DEG_OFF + N_NODES)
#define FP_OFF    (RP_OFF + N_NODES + 1)
#define POSI_OFF  (FP_OFF + N_NODES)
#define POSJ_OFF  (POSI_OFF + N_EDGES)

typedef float f32x2 __attribute__((ext_vector_type(2)));
typedef __fp16 fp16x2 __attribute__((ext_vector_type(2)));

__device__ __forceinline__ unsigned pkrtz(float a, float b) {
    fp16x2 h = __builtin_amdgcn_cvt_pkrtz(a, b);
    return *(unsigned*)&h;
}

// quad-perm broadcast of slot SLOT within each aligned 4-lane group (VALU DPP, no LDS)
template<int SLOT>
__device__ __forceinline__ float qb(float x) {
    int r = __builtin_amdgcn_update_dpp(0, __float_as_int(x), SLOT * 0x55, 0xf, 0xf, true);
    return __int_as_float(r);
}
// quad-perm [2,3,0,1]: exchange lanes q <-> q^2
__device__ __forceinline__ float qswap2(float x) {
    int r = __builtin_amdgcn_update_dpp(0, __float_as_int(x), 0x4E, 0xf, 0xf, true);
    return __int_as_float(r);
}

__device__ __forceinline__ void vrelu_p(float& a0, f32x2& a12,
                                        float q0, f32x2 q12, float iq2) {
    float t = fmaf(a0, q0, fmaf(a12.x, q12.x, a12.y * q12.y));
    float r = t > 0.f ? t * iq2 : 0.f;
    a0 = fmaf(-r, q0, a0);
    f32x2 nr = {-r, -r};
    a12 = nr * q12 + a12;
}

__device__ __forceinline__ void vrelu3(float& x0, float& x1, float& x2,
                                       float q0, float q1, float q2, float iq2) {
    float t = x0*q0 + x1*q1 + x2*q2;
    float r = t > 0.f ? t*iq2 : 0.f;
    x0 = fmaf(-r, q0, x0);
    x1 = fmaf(-r, q1, x1);
    x2 = fmaf(-r, q2, x2);
}

// one quarter of the 36-channel matvec: input channels [QS*9, QS*9+9) broadcast
// from quad slot QS; this thread accumulates its own 9 output channels.
// class 0 accumulators packed as 4x f32x2 + 1 scalar (v_pk_fma_f32).
template<int QS>
__device__ __forceinline__ void matvec_part(const float* __restrict__ mbase, int q,
        const float (&v0)[9], const f32x2 (&v12)[9],
        f32x2 (&a0p)[4], float& a0s, f32x2 (&a12)[9]) {
    const float* rb = mbase + QS*720 + q*20;
#pragma unroll
    for (int kc = 0; kc < 9; ++kc) {
        float b0 = qb<QS>(v0[kc]);
        f32x2 b12; b12.x = qb<QS>(v12[kc].x); b12.y = qb<QS>(v12[kc].y);
        f32x2 bb0 = {b0, b0};
        const float4* rp = (const float4*)(rb + kc*80);
        float4 R0 = rp[0], R1 = rp[1], R2 = rp[2], R3 = rp[3], R4 = rp[4];
        f32x2 m0p[4] = {{R0.x,R0.y},{R0.z,R0.w},{R1.x,R1.y},{R1.z,R1.w}};
        float mA[9] = {R2.z,R2.w,R3.x,R3.y,R3.z,R3.w,R4.x,R4.y,R4.z};
#pragma unroll
        for (int k = 0; k < 4; ++k) a0p[k] = m0p[k] * bb0 + a0p[k];
        a0s = fmaf(R2.x, b0, a0s);
#pragma unroll
        for (int k = 0; k < 9; ++k) {
            f32x2 mm = {mA[k], mA[k]};
            a12[k] = mm * b12 + a12[k];
        }
    }
}

// ---------------- precompute reduced matrices (+ zero deg) ----------------
__global__ void precompute_kernel(const float* __restrict__ K2N,
                                  const float* __restrict__ K2E,
                                  const float* __restrict__ KE1,
                                  const float* __restrict__ KE2,
                                  const float* __restrict__ KNc,
                                  float* __restrict__ ws,
                                  int* __restrict__ deg) {
    int tid = blockIdx.x * blockDim.x + threadIdx.x;
    int nthr = gridDim.x * blockDim.x;
    if (tid < N_NODES) deg[tid] = 0;
    for (int m = tid; m < 1440; m += nthr) {
        ws[MIT_OFF + m*20 + 9]  = 0.f;
        ws[MIT_OFF + m*20 + 19] = 0.f;
    }
    for (int m = tid; m < 5*1296; m += nthr) {
        int l = m / 1296, oc = m % 1296;
        int o = oc / 36, c = oc % 36;
        int qq = o / 9, k = o % 9;
        const float* p1 = KE1 + (size_t)(l*1296 + oc)*6;
        const float* p2 = KE2 + (size_t)(l*1296 + oc)*6;
        int base = MIT_OFF + l*5760 + (c*4 + qq)*20;
        ws[base + k]             = p1[0] + p1[1] + p1[2];
        ws[base + 10 + k]        = p1[3] + p1[4] + p1[5];
        ws[base + 2880 + k]      = p2[0] + p2[1] + p2[2];
        ws[base + 2880 + 10 + k] = p2[3] + p2[4] + p2[5];
    }
    for (int m = tid; m < 2*256; m += nthr) {
        int s = m / 256, oc = m % 256;
        const float* p = K2N + oc*6 + 3*s;
        ws[K2N_OFF + m] = p[0] + p[1] + p[2];
    }
    for (int m = tid; m < 2*54; m += nthr) {
        int s = m / 54, oc = m % 54;
        const float* p = KNc + oc*6 + 3*s;
        ws[KNC_OFF + m] = p[0] + p[1] + p[2];
    }
    if (tid < 2) {
        const float* p = K2E + 3*tid;
        ws[K2E_OFF + tid] = p[0] + p[1] + p[2];
    }
}

// ---------------- CSR build ----------------
__global__ void count_kernel(const int* __restrict__ iInd, const int* __restrict__ jInd,
                             int* __restrict__ deg) {
    int e = blockIdx.x * blockDim.x + threadIdx.x;
    if (e >= N_EDGES) return;
    atomicAdd(&deg[iInd[e]], 1);
    atomicAdd(&deg[jInd[e]], 1);
}

__global__ void scan_kernel(const int* __restrict__ deg, int* __restrict__ rowptr,
                            int* __restrict__ fpos) {
    __shared__ int lds[256];
    int t = threadIdx.x;
    int base = t * 32;
    int s = 0;
#pragma unroll
    for (int k = 0; k < 32; ++k) s += deg[base + k];
    lds[t] = s;
    __syncthreads();
    if (t == 0) {
        int run = 0;
        for (int k = 0; k < 256; ++k) { int v = lds[k]; lds[k] = run; run += v; }
        rowptr[N_NODES] = run;
    }
    __syncthreads();
    int off = lds[t];
#pragma unroll
    for (int k = 0; k < 32; ++k) {
        rowptr[base + k] = off;
        fpos[base + k] = off;
        off += deg[base + k];
    }
}

__global__ void fill_kernel(const int* __restrict__ iInd, const int* __restrict__ jInd,
                            int* __restrict__ fpos,
                            int* __restrict__ posI, int* __restrict__ posJ) {
    int e = blockIdx.x * blockDim.x + threadIdx.x;
    if (e >= N_EDGES) return;
    posI[e] = atomicAdd(&fpos[iInd[e]], 1);
    posJ[e] = atomicAdd(&fpos[jInd[e]], 1);
}

// ---------------- opening: node (blocks 0..31) + edge (blocks 32..287) ----------------
__global__ void open_kernel(const float* __restrict__ xnV,
                            const float* __restrict__ xeV,
                            const float* __restrict__ Q,
                            const float* __restrict__ K1N,
                            const float* __restrict__ K1E,
                            const float* __restrict__ ws,
                            const int* __restrict__ posI, const int* __restrict__ posJ,
                            float* __restrict__ xn3,
                            float4* __restrict__ seslot) {
    float q0 = Q[0], q1 = Q[1], q2 = Q[2];
    float iq2 = 1.f / (q0*q0 + q1*q1 + q2*q2);

    if (blockIdx.x < 32) {
        int n = blockIdx.x * 256 + threadIdx.x;
        float R[3][9];
#pragma unroll
        for (int c = 0; c < 3; ++c)
#pragma unroll
            for (int p = 0; p < 9; ++p)
                R[c][p] = xnV[(c*9 + p)*N_NODES + n];
#pragma unroll
        for (int c = 0; c < 3; ++c)
#pragma unroll
            for (int v = 0; v < 3; ++v)
                vrelu3(R[c][3*v], R[c][3*v+1], R[c][3*v+2], q0, q1, q2, iq2);

        float s[16][3];
#pragma unroll
        for (int o = 0; o < 16; ++o) {
            float a0 = 0.f, a1 = 0.f, a2 = 0.f;
#pragma unroll
            for (int c = 0; c < 3; ++c)
#pragma unroll
                for (int g = 0; g < 3; ++g) {
                    a0 = fmaf(R[c][3*g + 0], K1N[(o*3 + c)*6 + g],     a0);
                    a1 = fmaf(R[c][3*g + 1], K1N[(o*3 + c)*6 + 3 + g], a1);
                    a2 = fmaf(R[c][3*g + 2], K1N[(o*3 + c)*6 + 3 + g], a2);
                }
            s[o][0] = a0; s[o][1] = a1; s[o][2] = a2;
        }
#pragma unroll
        for (int o = 0; o < 16; ++o)
            vrelu3(s[o][0], s[o][1], s[o][2], q0, q1, q2, iq2);

        float u[16][3];
#pragma unroll
        for (int o = 0; o < 16; ++o) {
            float a0 = 0.f, a1 = 0.f, a2 = 0.f;
#pragma unroll
            for (int c = 0; c < 16; ++c) {
                float m0 = ws[K2N_OFF + o*16 + c];
                float mA = ws[K2N_OFF + 256 + o*16 + c];
                a0 = fmaf(m0, s[c][0], a0);
                a1 = fmaf(mA, s[c][1], a1);
                a2 = fmaf(mA, s[c][2], a2);
            }
            u[o][0] = a0; u[o][1] = a1; u[o][2] = a2;
            vrelu3(u[o][0], u[o][1], u[o][2], q0, q1, q2, iq2);
        }

        float* dst = xn3 + n*NS;
#pragma unroll
        for (int o = 0; o < 16; ++o) {
            int base = (o/9)*28 + (o%9)*3;
#pragma unroll
            for (int g = 0; g < 3; ++g)
                dst[base + g] = u[o][g];
        }
        dst[27] = 0.f;
    } else {
        int e = (blockIdx.x - 32) * 256 + threadIdx.x;
        float R[9];
#pragma unroll
        for (int p = 0; p < 9; ++p) R[p] = xeV[p*N_EDGES + e];
#pragma unroll
        for (int v = 0; v < 3; ++v)
            vrelu3(R[3*v], R[3*v+1], R[3*v+2], q0, q1, q2, iq2);

        float s0 = 0.f, s1 = 0.f, s2 = 0.f;
#pragma unroll
        for (int g = 0; g < 3; ++g) {
            s0 = fmaf(R[3*g + 0], K1E[g],     s0);
            s1 = fmaf(R[3*g + 1], K1E[3 + g], s1);
            s2 = fmaf(R[3*g + 2], K1E[3 + g], s2);
        }
        vrelu3(s0, s1, s2, q0, q1, q2, iq2);
        s0 *= ws[K2E_OFF + 0];
        s1 *= ws[K2E_OFF + 1];
        s2 *= ws[K2E_OFF + 1];
        vrelu3(s0, s1, s2, q0, q1, q2, iq2);

        // slot stores div contribution + sign (ave = 0.5*sign*div)
        seslot[posI[e]] = make_float4( s0,  s1,  s2,  1.f);
        seslot[posJ[e]] = make_float4(-s0, -s1, -s2, -1.f);
    }
}

// gather edge-open contributions into xn3 channels 16,17 — streaming CSR reads
__global__ void open_gather_kernel(const float4* __restrict__ seslot,
                                   const int* __restrict__ rowptr,
                                   float* __restrict__ xn3) {
    int n = blockIdx.x * blockDim.x + threadIdx.x;
    if (n >= N_NODES) return;
    int beg = rowptr[n], end = rowptr[n + 1];
    float d0 = 0.f, d1 = 0.f, d2 = 0.f, a0 = 0.f, a1 = 0.f, a2 = 0.f;
    for (int d = beg; d < end; ++d) {
        float4 v = seslot[d];
        d0 += v.x; d1 += v.y; d2 += v.z;
        float hs = 0.5f * v.w;
        a0 = fmaf(hs, v.x, a0); a1 = fmaf(hs, v.y, a1); a2 = fmaf(hs, v.z, a2);
    }
    float* dst = xn3 + n*NS;
    dst[49] = d0; dst[50] = d1; dst[51] = d2;
    dst[52] = a0; dst[53] = a1; dst[54] = a2;
    dst[55] = 0.f;
}

// ---------------- per-layer phase A: 4 threads/edge, fp16 line-exact CSR-slot output ----------------
// launch_bounds (256, 2): cap 256 VGPRs — kernel needs ~100 live floats; the (256,4)
// bound forced a 64-reg allocation with scratch spills in the 72-iter inner loop
// (round-5 counters: FETCH 34MB/WRITE 82MB of spill traffic).
template<bool WRITE_FLUX>
__global__ __launch_bounds__(256, 2) void edge_compute_kernel(
        const float* __restrict__ xn3,
        const int* __restrict__ iInd, const int* __restrict__ jInd,
        const int* __restrict__ posI, const int* __restrict__ posJ,
        const float* __restrict__ Q,
        const float* __restrict__ mitg,   // [2][36][4][20]
        unsigned* __restrict__ flux16, float* __restrict__ fluxOut) {
    __shared__ float mit[5760];
    {
        const float4* s4 = (const float4*)mitg;
        float4* d4 = (float4*)mit;
        for (int t = threadIdx.x; t < 1440; t += 256) d4[t] = s4[t];
    }
    __syncthreads();

    int tid = blockIdx.x * 256 + threadIdx.x;
    int e = tid >> 2, q = tid & 3;
    float q0 = Q[0];
    f32x2 q12 = {Q[1], Q[2]};
    float iq2 = 1.f / (q0*q0 + q12.x*q12.x + q12.y*q12.y);
    int i = iInd[e], j = jInd[e];
    const float4* xi = (const float4*)(xn3 + i*NS + 28*(q & 1));
    const float4* xj = (const float4*)(xn3 + j*NS + 28*(q & 1));

    bool isAve = q >= 2;
    float sA = isAve ? 0.5f :  1.f;
    float sB = isAve ? 0.5f : -1.f;

    // fused gather + grad/ave combine: never materialize A[28]/B[28]
    float vv[28];
#pragma unroll
    for (int t = 0; t < 7; ++t) {
        float4 a = xi[t], b = xj[t];
        vv[4*t+0] = fmaf(sA, a.x, sB * b.x);
        vv[4*t+1] = fmaf(sA, a.y, sB * b.y);
        vv[4*t+2] = fmaf(sA, a.z, sB * b.z);
        vv[4*t+3] = fmaf(sA, a.w, sB * b.w);
    }

    float v0[9]; f32x2 v12[9];
#pragma unroll
    for (int k = 0; k < 9; ++k) {
        v0[k]    = vv[3*k];
        v12[k].x = vv[3*k+1];
        v12[k].y = vv[3*k+2];
        vrelu_p(v0[k], v12[k], q0, q12, iq2);
    }

    f32x2 a0p[4]; float a0s; f32x2 a12[9];
#pragma unroll
    for (int k = 0; k < 4; ++k) a0p[k] = (f32x2){0.f, 0.f};
    a0s = 0.f;
#pragma unroll
    for (int k = 0; k < 9; ++k) a12[k] = (f32x2){0.f, 0.f};
    matvec_part<0>(mit, q, v0, v12, a0p, a0s, a12);
    matvec_part<1>(mit, q, v0, v12, a0p, a0s, a12);
    matvec_part<2>(mit, q, v0, v12, a0p, a0s, a12);
    matvec_part<3>(mit, q, v0, v12, a0p, a0s, a12);
#pragma unroll
    for (int k = 0; k < 9; ++k) {
        float w0 = (k < 8) ? ((k & 1) ? a0p[k>>1].y : a0p[k>>1].x) : a0s;
        f32x2 w12 = a12[k];
        vrelu_p(w0, w12, q0, q12, iq2);
        v0[k] = w0; v12[k] = w12;
    }
#pragma unroll
    for (int k = 0; k < 4; ++k) a0p[k] = (f32x2){0.f, 0.f};
    a0s = 0.f;
#pragma unroll
    for (int k = 0; k < 9; ++k) a12[k] = (f32x2){0.f, 0.f};
    matvec_part<0>(mit + 2880, q, v0, v12, a0p, a0s, a12);
    matvec_part<1>(mit + 2880, q, v0, v12, a0p, a0s, a12);
    matvec_part<2>(mit + 2880, q, v0, v12, a0p, a0s, a12);
    matvec_part<3>(mit + 2880, q, v0, v12, a0p, a0s, a12);

    float w0[9]; f32x2 w12[9];
#pragma unroll
    for (int k = 0; k < 9; ++k) {
        w0[k] = (k < 8) ? ((k & 1) ? a0p[k>>1].y : a0p[k>>1].x) : a0s;
        w12[k] = a12[k];
        vrelu_p(w0[k], w12[k], q0, q12, iq2);
    }

    // pp (q<2): own(div) + 0.5*partner(ave);  pm (q>=2): 0.5*own(ave) - partner(div)
    float selO = (q < 2) ? 1.f  : 0.5f;
    float selP = (q < 2) ? 0.5f : -1.f;
    float outv[27];
#pragma unroll
    for (int k = 0; k < 9; ++k) {
        float o0 = qswap2(w0[k]);
        float o1 = qswap2(w12[k].x);
        float o2 = qswap2(w12[k].y);
        outv[3*k]   = fmaf(selO, w0[k],    selP * o0);
        outv[3*k+1] = fmaf(selO, w12[k].x, selP * o1);
        outv[3*k+2] = fmaf(selO, w12[k].y, selP * o2);
    }
    // pack 27 floats -> 16 u32 of fp16 pairs; quad covers one full 128B line per slot
    unsigned pk[16];
#pragma unroll
    for (int t = 0; t < 13; ++t) pk[t] = pkrtz(outv[2*t], outv[2*t+1]);
    pk[13] = pkrtz(outv[26], 0.f);
    pk[14] = 0u; pk[15] = 0u;
    int slot = (q < 2) ? posI[e] : posJ[e];
    uint4* dst = (uint4*)(flux16 + (size_t)slot*32 + (q & 1)*16);
    dst[0] = make_uint4(pk[0],  pk[1],  pk[2],  pk[3]);
    dst[1] = make_uint4(pk[4],  pk[5],  pk[6],  pk[7]);
    dst[2] = make_uint4(pk[8],  pk[9],  pk[10], pk[11]);
    dst[3] = make_uint4(pk[12], pk[13], pk[14], pk[15]);

    if (WRITE_FLUX) {
#pragma unroll
        for (int k = 0; k < 9; ++k) {
#pragma unroll
            for (int p = 0; p < 9; ++p) {
                float wv = (p % 3 == 0) ? w0[k] : (p % 3 == 1) ? w12[k].x : w12[k].y;
                fluxOut[((size_t)((9*q + k)*9 + p))*N_EDGES + e] = wv;
            }
        }
    }
}

// ---------------- per-layer phase B: wave-per-node streaming fp16 gather + xn update ----------------
__global__ __launch_bounds__(64) void node_gather_kernel(
        const __fp16* __restrict__ flux16,
        const int* __restrict__ rowptr,
        float* __restrict__ xn3) {
    int n = blockIdx.x;
    int l = threadIdx.x;
    int beg = rowptr[n], end = rowptr[n + 1];
    const __fp16* p = flux16 + (size_t)beg * 64 + l;
    float acc = 0.f, acc2 = 0.f;
    int d = beg;
    for (; d + 2 <= end; d += 2) {
        acc  += (float)p[0];
        acc2 += (float)p[64];
        p += 128;
    }
    if (d < end) acc += (float)p[0];
    acc += acc2;
    int m = l & 31;
    if (m < 27) {
        float* x = xn3 + n*NS + (l >> 5)*28 + m;
        *x = fmaf(-0.1f, acc, *x);
    }
}

// ---------------- closing layer ----------------
__global__ void close_kernel(const float* __restrict__ xn3,
                             const float* __restrict__ ws,
                             float* __restrict__ out) {
    int n = blockIdx.x * blockDim.x + threadIdx.x;
    if (n >= N_NODES) return;
    const float* x = xn3 + n*NS;
    float o[3][3];
#pragma unroll
    for (int oo = 0; oo < 3; ++oo) {
        float a0 = 0.f, a1 = 0.f, a2 = 0.f;
#pragma unroll
        for (int c = 0; c < 18; ++c) {
            int xidx = (c/9)*28 + (c%9)*3;
            float m0 = ws[KNC_OFF + oo*18 + c];
            float mA = ws[KNC_OFF + 54 + oo*18 + c];
            a0 = fmaf(m0, x[xidx + 0], a0);
            a1 = fmaf(mA, x[xidx + 1], a1);
            a2 = fmaf(mA, x[xidx + 2], a2);
        }
        o[oo][0] = a0; o[oo][1] = a1; o[oo][2] = a2;
    }
#pragma unroll
    for (int oo = 0; oo < 3; ++oo)
#pragma unroll
        for (int p = 0; p < 9; ++p)
            out[(oo*9 + p)*N_NODES + n] = o[oo][p % 3];
}

extern "C" void kernel_launch(void* const* d_in, const int* in_sizes, int n_in,
                              void* d_out, int out_size, void* d_ws, size_t ws_size,
                              hipStream_t stream) {
    const float* xnV = (const float*)d_in[0];
    const float* xeV = (const float*)d_in[1];
    const int*   iInd = (const int*)d_in[2];
    const int*   jInd = (const int*)d_in[3];
    const float* K1N = (const float*)d_in[4];
    const float* K2N = (const float*)d_in[5];
    const float* K1E = (const float*)d_in[6];
    const float* K2E = (const float*)d_in[7];
    const float* KE1 = (const float*)d_in[8];
    const float* KE2 = (const float*)d_in[9];
    const float* KNc = (const float*)d_in[10];
    const float* Q   = (const float*)d_in[11];

    float* ws   = (float*)d_ws;
    float* xn3  = ws + XN3_OFF;
    unsigned* flux16 = (unsigned*)(ws + FLUX_OFF);
    float4* se4 = (float4*)(ws + FLUX_OFF);       // overlays flux region (used only pre-layers)
    int* wsi    = (int*)d_ws;
    int* deg    = wsi + DEG_OFF;
    int* rowptr = wsi + RP_OFF;
    int* fpos   = wsi + FP_OFF;
    int* posI   = wsi + POSI_OFF;
    int* posJ   = wsi + POSJ_OFF;

    float* out  = (float*)d_out;
    float* fluxOut = out + 3*9*N_NODES;

    precompute_kernel<<<64, 256, 0, stream>>>(K2N, K2E, KE1, KE2, KNc, ws, deg);
    count_kernel<<<N_EDGES/256, 256, 0, stream>>>(iInd, jInd, deg);
    scan_kernel<<<1, 256, 0, stream>>>(deg, rowptr, fpos);
    fill_kernel<<<N_EDGES/256, 256, 0, stream>>>(iInd, jInd, fpos, posI, posJ);

    open_kernel<<<32 + N_EDGES/256, 256, 0, stream>>>(
        xnV, xeV, Q, K1N, K1E, ws, posI, posJ, xn3, se4);
    open_gather_kernel<<<N_NODES/256, 256, 0, stream>>>(se4, rowptr, xn3);

    for (int l = 0; l < 5; ++l) {
        const float* mitg = ws + MIT_OFF + l*5760;
        if (l == 4)
            edge_compute_kernel<true><<<N_EDGES*4/256, 256, 0, stream>>>(
                xn3, iInd, jInd, posI, posJ, Q, mitg, flux16, fluxOut);
        else
            edge_compute_kernel<false><<<N_EDGES*4/256, 256, 0, stream>>>(
                xn3, iInd, jInd, posI, posJ, Q, mitg, flux16, nullptr);
        node_gather_kernel<<<N_NODES, 64, 0, stream>>>((const __fp16*)flux16, rowptr, xn3);
    }

    close_kernel<<<N_NODES/256, 256, 0, stream>>>(xn3, ws, out);
}

// Round 9
// 268.959 us; speedup vs baseline: 8.0477x; 1.0441x over previous
//
#include <hip/hip_runtime.h>

// Problem constants (fixed by setup_inputs)
#define N_NODES 8192
#define N_EDGES 65536
#define NS 64    // node state: 2 halves of 32 floats (27 used + pad); ch c class g at (c/9)*32+(c%9)*3+g
// flux16: CSR-slot layout [2E slots][64 halves] — one 128B cache line per endpoint contribution.

// Workspace layout (word offsets into d_ws)
#define XN3_OFF   0                                   // [8192][64] floats
#define MIT_OFF   (N_NODES*NS)                        // [5][2 stages][36 c][4 q][20] floats
#define K2N_OFF   (MIT_OFF + 5*5760)                  // [2][16][16]
#define KNC_OFF   (K2N_OFF + 2*16*16)                 // [2][3][18]
#define K2E_OFF   (KNC_OFF + 2*3*18)                  // [2]
#define FLUX_OFF  553728                              // 16B-aligned; [2E][32] u32 (fp16 pairs)
#define FLUX_END  (FLUX_OFF + 2*N_EDGES*32)
#define DEG_OFF   FLUX_END
#define RP_OFF    (DEG_OFF + N_NODES)
#define FP_OFF    (RP_OFF + N_NODES + 1)
#define POSI_OFF  (FP_OFF + N_NODES)
#define POSJ_OFF  (POSI_OFF + N_EDGES)

typedef float f32x2 __attribute__((ext_vector_type(2)));
typedef __fp16 fp16x2 __attribute__((ext_vector_type(2)));

__device__ __forceinline__ unsigned pkrtz(float a, float b) {
    fp16x2 h = __builtin_amdgcn_cvt_pkrtz(a, b);
    return *(unsigned*)&h;
}

// quad-perm broadcast of slot SLOT within each aligned 4-lane group (VALU DPP, no LDS)
template<int SLOT>
__device__ __forceinline__ float qb(float x) {
    int r = __builtin_amdgcn_update_dpp(0, __float_as_int(x), SLOT * 0x55, 0xf, 0xf, true);
    return __int_as_float(r);
}
// quad-perm [2,3,0,1]: exchange lanes q <-> q^2
__device__ __forceinline__ float qswap2(float x) {
    int r = __builtin_amdgcn_update_dpp(0, __float_as_int(x), 0x4E, 0xf, 0xf, true);
    return __int_as_float(r);
}

__device__ __forceinline__ void vrelu_p(float& a0, f32x2& a12,
                                        float q0, f32x2 q12, float iq2) {
    float t = fmaf(a0, q0, fmaf(a12.x, q12.x, a12.y * q12.y));
    float r = t > 0.f ? t * iq2 : 0.f;
    a0 = fmaf(-r, q0, a0);
    f32x2 nr = {-r, -r};
    a12 = nr * q12 + a12;
}

__device__ __forceinline__ void vrelu3(float& x0, float& x1, float& x2,
                                       float q0, float q1, float q2, float iq2) {
    float t = x0*q0 + x1*q1 + x2*q2;
    float r = t > 0.f ? t*iq2 : 0.f;
    x0 = fmaf(-r, q0, x0);
    x1 = fmaf(-r, q1, x1);
    x2 = fmaf(-r, q2, x2);
}

// one quarter of the 36-channel matvec for TWO edges sharing each LDS matrix row read.
// Input channels [QS*9, QS*9+9) broadcast from quad slot QS; this thread accumulates
// its own 9 output channels for both edges. class 0 packed as 4x f32x2 + scalar.
template<int QS>
__device__ __forceinline__ void matvec2(const float* __restrict__ mbase, int q,
        const float (&v0a)[9], const f32x2 (&v12a)[9],
        const float (&v0b)[9], const f32x2 (&v12b)[9],
        f32x2 (&a0pa)[4], float& a0sa, f32x2 (&a12a)[9],
        f32x2 (&a0pb)[4], float& a0sb, f32x2 (&a12b)[9]) {
    const float* rb = mbase + QS*720 + q*20;
#pragma unroll
    for (int kc = 0; kc < 9; ++kc) {
        float b0a = qb<QS>(v0a[kc]);
        f32x2 b12a; b12a.x = qb<QS>(v12a[kc].x); b12a.y = qb<QS>(v12a[kc].y);
        float b0b = qb<QS>(v0b[kc]);
        f32x2 b12b; b12b.x = qb<QS>(v12b[kc].x); b12b.y = qb<QS>(v12b[kc].y);
        f32x2 bb0a = {b0a, b0a};
        f32x2 bb0b = {b0b, b0b};
        const float4* rp = (const float4*)(rb + kc*80);
        float4 R0 = rp[0], R1 = rp[1], R2 = rp[2], R3 = rp[3], R4 = rp[4];
        f32x2 m0p[4] = {{R0.x,R0.y},{R0.z,R0.w},{R1.x,R1.y},{R1.z,R1.w}};
        float mA[9] = {R2.z,R2.w,R3.x,R3.y,R3.z,R3.w,R4.x,R4.y,R4.z};
#pragma unroll
        for (int k = 0; k < 4; ++k) {
            a0pa[k] = m0p[k] * bb0a + a0pa[k];
            a0pb[k] = m0p[k] * bb0b + a0pb[k];
        }
        a0sa = fmaf(R2.x, b0a, a0sa);
        a0sb = fmaf(R2.x, b0b, a0sb);
#pragma unroll
        for (int k = 0; k < 9; ++k) {
            f32x2 mm = {mA[k], mA[k]};
            a12a[k] = mm * b12a + a12a[k];
            a12b[k] = mm * b12b + a12b[k];
        }
    }
}

// ---------------- precompute reduced matrices (+ zero deg) ----------------
__global__ void precompute_kernel(const float* __restrict__ K2N,
                                  const float* __restrict__ K2E,
                                  const float* __restrict__ KE1,
                                  const float* __restrict__ KE2,
                                  const float* __restrict__ KNc,
                                  float* __restrict__ ws,
                                  int* __restrict__ deg) {
    int tid = blockIdx.x * blockDim.x + threadIdx.x;
    int nthr = gridDim.x * blockDim.x;
    if (tid < N_NODES) deg[tid] = 0;
    for (int m = tid; m < 1440; m += nthr) {
        ws[MIT_OFF + m*20 + 9]  = 0.f;
        ws[MIT_OFF + m*20 + 19] = 0.f;
    }
    for (int m = tid; m < 5*1296; m += nthr) {
        int l = m / 1296, oc = m % 1296;
        int o = oc / 36, c = oc % 36;
        int qq = o / 9, k = o % 9;
        const float* p1 = KE1 + (size_t)(l*1296 + oc)*6;
        const float* p2 = KE2 + (size_t)(l*1296 + oc)*6;
        int base = MIT_OFF + l*5760 + (c*4 + qq)*20;
        ws[base + k]             = p1[0] + p1[1] + p1[2];
        ws[base + 10 + k]        = p1[3] + p1[4] + p1[5];
        ws[base + 2880 + k]      = p2[0] + p2[1] + p2[2];
        ws[base + 2880 + 10 + k] = p2[3] + p2[4] + p2[5];
    }
    for (int m = tid; m < 2*256; m += nthr) {
        int s = m / 256, oc = m % 256;
        const float* p = K2N + oc*6 + 3*s;
        ws[K2N_OFF + m] = p[0] + p[1] + p[2];
    }
    for (int m = tid; m < 2*54; m += nthr) {
        int s = m / 54, oc = m % 54;
        const float* p = KNc + oc*6 + 3*s;
        ws[KNC_OFF + m] = p[0] + p[1] + p[2];
    }
    if (tid < 2) {
        const float* p = K2E + 3*tid;
        ws[K2E_OFF + tid] = p[0] + p[1] + p[2];
    }
}

// ---------------- CSR build ----------------
__global__ void count_kernel(const int* __restrict__ iInd, const int* __restrict__ jInd,
                             int* __restrict__ deg) {
    int e = blockIdx.x * blockDim.x + threadIdx.x;
    if (e >= N_EDGES) return;
    atomicAdd(&deg[iInd[e]], 1);
    atomicAdd(&deg[jInd[e]], 1);
}

__global__ void scan_kernel(const int* __restrict__ deg, int* __restrict__ rowptr,
                            int* __restrict__ fpos) {
    __shared__ int lds[256];
    int t = threadIdx.x;
    int base = t * 32;
    int s = 0;
#pragma unroll
    for (int k = 0; k < 32; ++k) s += deg[base + k];
    lds[t] = s;
    __syncthreads();
    if (t == 0) {
        int run = 0;
        for (int k = 0; k < 256; ++k) { int v = lds[k]; lds[k] = run; run += v; }
        rowptr[N_NODES] = run;
    }
    __syncthreads();
    int off = lds[t];
#pragma unroll
    for (int k = 0; k < 32; ++k) {
        rowptr[base + k] = off;
        fpos[base + k] = off;
        off += deg[base + k];
    }
}

__global__ void fill_kernel(const int* __restrict__ iInd, const int* __restrict__ jInd,
                            int* __restrict__ fpos,
                            int* __restrict__ posI, int* __restrict__ posJ) {
    int e = blockIdx.x * blockDim.x + threadIdx.x;
    if (e >= N_EDGES) return;
    posI[e] = atomicAdd(&fpos[iInd[e]], 1);
    posJ[e] = atomicAdd(&fpos[jInd[e]], 1);
}

// ---------------- opening: node (blocks 0..31) + edge (blocks 32..287) ----------------
__global__ void open_kernel(const float* __restrict__ xnV,
                            const float* __restrict__ xeV,
                            const float* __restrict__ Q,
                            const float* __restrict__ K1N,
                            const float* __restrict__ K1E,
                            const float* __restrict__ ws,
                            const int* __restrict__ posI, const int* __restrict__ posJ,
                            float* __restrict__ xn3,
                            float4* __restrict__ seslot) {
    float q0 = Q[0], q1 = Q[1], q2 = Q[2];
    float iq2 = 1.f / (q0*q0 + q1*q1 + q2*q2);

    if (blockIdx.x < 32) {
        int n = blockIdx.x * 256 + threadIdx.x;
        float R[3][9];
#pragma unroll
        for (int c = 0; c < 3; ++c)
#pragma unroll
            for (int p = 0; p < 9; ++p)
                R[c][p] = xnV[(c*9 + p)*N_NODES + n];
#pragma unroll
        for (int c = 0; c < 3; ++c)
#pragma unroll
            for (int v = 0; v < 3; ++v)
                vrelu3(R[c][3*v], R[c][3*v+1], R[c][3*v+2], q0, q1, q2, iq2);

        float s[16][3];
#pragma unroll
        for (int o = 0; o < 16; ++o) {
            float a0 = 0.f, a1 = 0.f, a2 = 0.f;
#pragma unroll
            for (int c = 0; c < 3; ++c)
#pragma unroll
                for (int g = 0; g < 3; ++g) {
                    a0 = fmaf(R[c][3*g + 0], K1N[(o*3 + c)*6 + g],     a0);
                    a1 = fmaf(R[c][3*g + 1], K1N[(o*3 + c)*6 + 3 + g], a1);
                    a2 = fmaf(R[c][3*g + 2], K1N[(o*3 + c)*6 + 3 + g], a2);
                }
            s[o][0] = a0; s[o][1] = a1; s[o][2] = a2;
        }
#pragma unroll
        for (int o = 0; o < 16; ++o)
            vrelu3(s[o][0], s[o][1], s[o][2], q0, q1, q2, iq2);

        float u[16][3];
#pragma unroll
        for (int o = 0; o < 16; ++o) {
            float a0 = 0.f, a1 = 0.f, a2 = 0.f;
#pragma unroll
            for (int c = 0; c < 16; ++c) {
                float m0 = ws[K2N_OFF + o*16 + c];
                float mA = ws[K2N_OFF + 256 + o*16 + c];
                a0 = fmaf(m0, s[c][0], a0);
                a1 = fmaf(mA, s[c][1], a1);
                a2 = fmaf(mA, s[c][2], a2);
            }
            u[o][0] = a0; u[o][1] = a1; u[o][2] = a2;
            vrelu3(u[o][0], u[o][1], u[o][2], q0, q1, q2, iq2);
        }

        float* dst = xn3 + n*NS;
#pragma unroll
        for (int o = 0; o < 16; ++o) {
            int base = (o/9)*32 + (o%9)*3;
#pragma unroll
            for (int g = 0; g < 3; ++g)
                dst[base + g] = u[o][g];
        }
#pragma unroll
        for (int k = 27; k < 32; ++k) dst[k] = 0.f;
    } else {
        int e = (blockIdx.x - 32) * 256 + threadIdx.x;
        float R[9];
#pragma unroll
        for (int p = 0; p < 9; ++p) R[p] = xeV[p*N_EDGES + e];
#pragma unroll
        for (int v = 0; v < 3; ++v)
            vrelu3(R[3*v], R[3*v+1], R[3*v+2], q0, q1, q2, iq2);

        float s0 = 0.f, s1 = 0.f, s2 = 0.f;
#pragma unroll
        for (int g = 0; g < 3; ++g) {
            s0 = fmaf(R[3*g + 0], K1E[g],     s0);
            s1 = fmaf(R[3*g + 1], K1E[3 + g], s1);
            s2 = fmaf(R[3*g + 2], K1E[3 + g], s2);
        }
        vrelu3(s0, s1, s2, q0, q1, q2, iq2);
        s0 *= ws[K2E_OFF + 0];
        s1 *= ws[K2E_OFF + 1];
        s2 *= ws[K2E_OFF + 1];
        vrelu3(s0, s1, s2, q0, q1, q2, iq2);

        // slot stores div contribution + sign (ave = 0.5*sign*div)
        seslot[posI[e]] = make_float4( s0,  s1,  s2,  1.f);
        seslot[posJ[e]] = make_float4(-s0, -s1, -s2, -1.f);
    }
}

// gather edge-open contributions into xn3 channels 16,17 — streaming CSR reads
__global__ void open_gather_kernel(const float4* __restrict__ seslot,
                                   const int* __restrict__ rowptr,
                                   float* __restrict__ xn3) {
    int n = blockIdx.x * blockDim.x + threadIdx.x;
    if (n >= N_NODES) return;
    int beg = rowptr[n], end = rowptr[n + 1];
    float d0 = 0.f, d1 = 0.f, d2 = 0.f, a0 = 0.f, a1 = 0.f, a2 = 0.f;
    for (int d = beg; d < end; ++d) {
        float4 v = seslot[d];
        d0 += v.x; d1 += v.y; d2 += v.z;
        float hs = 0.5f * v.w;
        a0 = fmaf(hs, v.x, a0); a1 = fmaf(hs, v.y, a1); a2 = fmaf(hs, v.z, a2);
    }
    float* dst = xn3 + n*NS;
    // ch16 -> half1 idx 21..23 (global 53..55), ch17 -> 24..26 (56..58)
    dst[53] = d0; dst[54] = d1; dst[55] = d2;
    dst[56] = a0; dst[57] = a1; dst[58] = a2;
#pragma unroll
    for (int k = 59; k < 64; ++k) dst[k] = 0.f;
}

// ---------------- per-layer phase A: 2 edges per thread-quad member ----------------
// Each LDS matrix-row read feeds FMAs for BOTH edges — halves the dominant LDS traffic.
template<bool WRITE_FLUX>
__global__ __launch_bounds__(256, 2) void edge_compute_kernel(
        const float* __restrict__ xn3,
        const int* __restrict__ iInd, const int* __restrict__ jInd,
        const int* __restrict__ posI, const int* __restrict__ posJ,
        const float* __restrict__ Q,
        const float* __restrict__ mitg,   // [2][36][4][20]
        unsigned* __restrict__ flux16, float* __restrict__ fluxOut) {
    __shared__ float mit[5760];
    {
        const float4* s4 = (const float4*)mitg;
        float4* d4 = (float4*)mit;
        for (int t = threadIdx.x; t < 1440; t += 256) d4[t] = s4[t];
    }
    __syncthreads();

    int tid = blockIdx.x * 256 + threadIdx.x;
    int qd = tid >> 2, q = tid & 3;
    int e0 = qd << 1, e1 = e0 | 1;
    float q0 = Q[0];
    f32x2 q12 = {Q[1], Q[2]};
    float iq2 = 1.f / (q0*q0 + q12.x*q12.x + q12.y*q12.y);
    int hofs = 32*(q & 1);
    const float4* xi0 = (const float4*)(xn3 + iInd[e0]*NS + hofs);
    const float4* xj0 = (const float4*)(xn3 + jInd[e0]*NS + hofs);
    const float4* xi1 = (const float4*)(xn3 + iInd[e1]*NS + hofs);
    const float4* xj1 = (const float4*)(xn3 + jInd[e1]*NS + hofs);

    bool isAve = q >= 2;
    float sA = isAve ? 0.5f :  1.f;
    float sB = isAve ? 0.5f : -1.f;

    // fused gather + grad/ave combine for both edges
    float vvA[28], vvB[28];
#pragma unroll
    for (int t = 0; t < 7; ++t) {
        float4 a = xi0[t], b = xj0[t];
        vvA[4*t+0] = fmaf(sA, a.x, sB * b.x);
        vvA[4*t+1] = fmaf(sA, a.y, sB * b.y);
        vvA[4*t+2] = fmaf(sA, a.z, sB * b.z);
        vvA[4*t+3] = fmaf(sA, a.w, sB * b.w);
        float4 c = xi1[t], d = xj1[t];
        vvB[4*t+0] = fmaf(sA, c.x, sB * d.x);
        vvB[4*t+1] = fmaf(sA, c.y, sB * d.y);
        vvB[4*t+2] = fmaf(sA, c.z, sB * d.z);
        vvB[4*t+3] = fmaf(sA, c.w, sB * d.w);
    }

    float v0a[9], v0b[9]; f32x2 v12a[9], v12b[9];
#pragma unroll
    for (int k = 0; k < 9; ++k) {
        v0a[k]    = vvA[3*k];
        v12a[k].x = vvA[3*k+1];
        v12a[k].y = vvA[3*k+2];
        vrelu_p(v0a[k], v12a[k], q0, q12, iq2);
        v0b[k]    = vvB[3*k];
        v12b[k].x = vvB[3*k+1];
        v12b[k].y = vvB[3*k+2];
        vrelu_p(v0b[k], v12b[k], q0, q12, iq2);
    }

    f32x2 a0pa[4], a0pb[4]; float a0sa, a0sb; f32x2 a12a[9], a12b[9];
#pragma unroll
    for (int k = 0; k < 4; ++k) { a0pa[k] = (f32x2){0.f,0.f}; a0pb[k] = (f32x2){0.f,0.f}; }
    a0sa = 0.f; a0sb = 0.f;
#pragma unroll
    for (int k = 0; k < 9; ++k) { a12a[k] = (f32x2){0.f,0.f}; a12b[k] = (f32x2){0.f,0.f}; }
    matvec2<0>(mit, q, v0a, v12a, v0b, v12b, a0pa, a0sa, a12a, a0pb, a0sb, a12b);
    matvec2<1>(mit, q, v0a, v12a, v0b, v12b, a0pa, a0sa, a12a, a0pb, a0sb, a12b);
    matvec2<2>(mit, q, v0a, v12a, v0b, v12b, a0pa, a0sa, a12a, a0pb, a0sb, a12b);
    matvec2<3>(mit, q, v0a, v12a, v0b, v12b, a0pa, a0sa, a12a, a0pb, a0sb, a12b);
#pragma unroll
    for (int k = 0; k < 9; ++k) {
        float w0 = (k < 8) ? ((k & 1) ? a0pa[k>>1].y : a0pa[k>>1].x) : a0sa;
        f32x2 w12 = a12a[k];
        vrelu_p(w0, w12, q0, q12, iq2);
        v0a[k] = w0; v12a[k] = w12;
        float u0 = (k < 8) ? ((k & 1) ? a0pb[k>>1].y : a0pb[k>>1].x) : a0sb;
        f32x2 u12 = a12b[k];
        vrelu_p(u0, u12, q0, q12, iq2);
        v0b[k] = u0; v12b[k] = u12;
    }
#pragma unroll
    for (int k = 0; k < 4; ++k) { a0pa[k] = (f32x2){0.f,0.f}; a0pb[k] = (f32x2){0.f,0.f}; }
    a0sa = 0.f; a0sb = 0.f;
#pragma unroll
    for (int k = 0; k < 9; ++k) { a12a[k] = (f32x2){0.f,0.f}; a12b[k] = (f32x2){0.f,0.f}; }
    matvec2<0>(mit + 2880, q, v0a, v12a, v0b, v12b, a0pa, a0sa, a12a, a0pb, a0sb, a12b);
    matvec2<1>(mit + 2880, q, v0a, v12a, v0b, v12b, a0pa, a0sa, a12a, a0pb, a0sb, a12b);
    matvec2<2>(mit + 2880, q, v0a, v12a, v0b, v12b, a0pa, a0sa, a12a, a0pb, a0sb, a12b);
    matvec2<3>(mit + 2880, q, v0a, v12a, v0b, v12b, a0pa, a0sa, a12a, a0pb, a0sb, a12b);

    // final relu into v0*/v12* (reuse as w)
#pragma unroll
    for (int k = 0; k < 9; ++k) {
        float w0 = (k < 8) ? ((k & 1) ? a0pa[k>>1].y : a0pa[k>>1].x) : a0sa;
        f32x2 w12 = a12a[k];
        vrelu_p(w0, w12, q0, q12, iq2);
        v0a[k] = w0; v12a[k] = w12;
        float u0 = (k < 8) ? ((k & 1) ? a0pb[k>>1].y : a0pb[k>>1].x) : a0sb;
        f32x2 u12 = a12b[k];
        vrelu_p(u0, u12, q0, q12, iq2);
        v0b[k] = u0; v12b[k] = u12;
    }

    // pp (q<2): own(div) + 0.5*partner(ave);  pm (q>=2): 0.5*own(ave) - partner(div)
    float selO = (q < 2) ? 1.f  : 0.5f;
    float selP = (q < 2) ? 0.5f : -1.f;
    {
        unsigned pk[16];
#pragma unroll
        for (int k = 0; k < 9; ++k) {
            float o0 = qswap2(v0a[k]);
            float o1 = qswap2(v12a[k].x);
            float o2 = qswap2(v12a[k].y);
            vvA[3*k]   = fmaf(selO, v0a[k],    selP * o0);
            vvA[3*k+1] = fmaf(selO, v12a[k].x, selP * o1);
            vvA[3*k+2] = fmaf(selO, v12a[k].y, selP * o2);
        }
#pragma unroll
        for (int t = 0; t < 13; ++t) pk[t] = pkrtz(vvA[2*t], vvA[2*t+1]);
        pk[13] = pkrtz(vvA[26], 0.f);
        pk[14] = 0u; pk[15] = 0u;
        int slot = (q < 2) ? posI[e0] : posJ[e0];
        uint4* dst = (uint4*)(flux16 + (size_t)slot*32 + (q & 1)*16);
        dst[0] = make_uint4(pk[0],  pk[1],  pk[2],  pk[3]);
        dst[1] = make_uint4(pk[4],  pk[5],  pk[6],  pk[7]);
        dst[2] = make_uint4(pk[8],  pk[9],  pk[10], pk[11]);
        dst[3] = make_uint4(pk[12], pk[13], pk[14], pk[15]);
    }
    {
        unsigned pk[16];
#pragma unroll
        for (int k = 0; k < 9; ++k) {
            float o0 = qswap2(v0b[k]);
            float o1 = qswap2(v12b[k].x);
            float o2 = qswap2(v12b[k].y);
            vvB[3*k]   = fmaf(selO, v0b[k],    selP * o0);
            vvB[3*k+1] = fmaf(selO, v12b[k].x, selP * o1);
            vvB[3*k+2] = fmaf(selO, v12b[k].y, selP * o2);
        }
#pragma unroll
        for (int t = 0; t < 13; ++t) pk[t] = pkrtz(vvB[2*t], vvB[2*t+1]);
        pk[13] = pkrtz(vvB[26], 0.f);
        pk[14] = 0u; pk[15] = 0u;
        int slot = (q < 2) ? posI[e1] : posJ[e1];
        uint4* dst = (uint4*)(flux16 + (size_t)slot*32 + (q & 1)*16);
        dst[0] = make_uint4(pk[0],  pk[1],  pk[2],  pk[3]);
        dst[1] = make_uint4(pk[4],  pk[5],  pk[6],  pk[7]);
        dst[2] = make_uint4(pk[8],  pk[9],  pk[10], pk[11]);
        dst[3] = make_uint4(pk[12], pk[13], pk[14], pk[15]);
    }

    if (WRITE_FLUX) {
#pragma unroll
        for (int k = 0; k < 9; ++k) {
#pragma unroll
            for (int p = 0; p < 9; ++p) {
                float wa = (p % 3 == 0) ? v0a[k] : (p % 3 == 1) ? v12a[k].x : v12a[k].y;
                fluxOut[((size_t)((9*q + k)*9 + p))*N_EDGES + e0] = wa;
                float wb = (p % 3 == 0) ? v0b[k] : (p % 3 == 1) ? v12b[k].x : v12b[k].y;
                fluxOut[((size_t)((9*q + k)*9 + p))*N_EDGES + e1] = wb;
            }
        }
    }
}

// ---------------- per-layer phase B: wave-per-node streaming fp16 gather + xn update ----------------
__global__ __launch_bounds__(64) void node_gather_kernel(
        const __fp16* __restrict__ flux16,
        const int* __restrict__ rowptr,
        float* __restrict__ xn3) {
    int n = blockIdx.x;
    int l = threadIdx.x;
    int beg = rowptr[n], end = rowptr[n + 1];
    const __fp16* p = flux16 + (size_t)beg * 64 + l;
    float acc = 0.f, acc2 = 0.f;
    int d = beg;
    for (; d + 2 <= end; d += 2) {
        acc  += (float)p[0];
        acc2 += (float)p[64];
        p += 128;
    }
    if (d < end) acc += (float)p[0];
    acc += acc2;
    if ((l & 31) < 27) {
        float* x = xn3 + n*NS + l;
        *x = fmaf(-0.1f, acc, *x);
    }
}

// ---------------- closing layer ----------------
__global__ void close_kernel(const float* __restrict__ xn3,
                             const float* __restrict__ ws,
                             float* __restrict__ out) {
    int n = blockIdx.x * blockDim.x + threadIdx.x;
    if (n >= N_NODES) return;
    const float* x = xn3 + n*NS;
    float o[3][3];
#pragma unroll
    for (int oo = 0; oo < 3; ++oo) {
        float a0 = 0.f, a1 = 0.f, a2 = 0.f;
#pragma unroll
        for (int c = 0; c < 18; ++c) {
            int xidx = (c/9)*32 + (c%9)*3;
            float m0 = ws[KNC_OFF + oo*18 + c];
            float mA = ws[KNC_OFF + 54 + oo*18 + c];
            a0 = fmaf(m0, x[xidx + 0], a0);
            a1 = fmaf(mA, x[xidx + 1], a1);
            a2 = fmaf(mA, x[xidx + 2], a2);
        }
        o[oo][0] = a0; o[oo][1] = a1; o[oo][2] = a2;
    }
#pragma unroll
    for (int oo = 0; oo < 3; ++oo)
#pragma unroll
        for (int p = 0; p < 9; ++p)
            out[(oo*9 + p)*N_NODES + n] = o[oo][p % 3];
}

extern "C" void kernel_launch(void* const* d_in, const int* in_sizes, int n_in,
                              void* d_out, int out_size, void* d_ws, size_t ws_size,
                              hipStream_t stream) {
    const float* xnV = (const float*)d_in[0];
    const float* xeV = (const float*)d_in[1];
    const int*   iInd = (const int*)d_in[2];
    const int*   jInd = (const int*)d_in[3];
    const float* K1N = (const float*)d_in[4];
    const float* K2N = (const float*)d_in[5];
    const float* K1E = (const float*)d_in[6];
    const float* K2E = (const float*)d_in[7];
    const float* KE1 = (const float*)d_in[8];
    const float* KE2 = (const float*)d_in[9];
    const float* KNc = (const float*)d_in[10];
    const float* Q   = (const float*)d_in[11];

    float* ws   = (float*)d_ws;
    float* xn3  = ws + XN3_OFF;
    unsigned* flux16 = (unsigned*)(ws + FLUX_OFF);
    float4* se4 = (float4*)(ws + FLUX_OFF);       // overlays flux region (used only pre-layers)
    int* wsi    = (int*)d_ws;
    int* deg    = wsi + DEG_OFF;
    int* rowptr = wsi + RP_OFF;
    int* fpos   = wsi + FP_OFF;
    int* posI   = wsi + POSI_OFF;
    int* posJ   = wsi + POSJ_OFF;

    float* out  = (float*)d_out;
    float* fluxOut = out + 3*9*N_NODES;

    precompute_kernel<<<64, 256, 0, stream>>>(K2N, K2E, KE1, KE2, KNc, ws, deg);
    count_kernel<<<N_EDGES/256, 256, 0, stream>>>(iInd, jInd, deg);
    scan_kernel<<<1, 256, 0, stream>>>(deg, rowptr, fpos);
    fill_kernel<<<N_EDGES/256, 256, 0, stream>>>(iInd, jInd, fpos, posI, posJ);

    open_kernel<<<32 + N_EDGES/256, 256, 0, stream>>>(
        xnV, xeV, Q, K1N, K1E, ws, posI, posJ, xn3, se4);
    open_gather_kernel<<<N_NODES/256, 256, 0, stream>>>(se4, rowptr, xn3);

    for (int l = 0; l < 5; ++l) {
        const float* mitg = ws + MIT_OFF + l*5760;
        if (l == 4)
            edge_compute_kernel<true><<<N_EDGES*2/256, 256, 0, stream>>>(
                xn3, iInd, jInd, posI, posJ, Q, mitg, flux16, fluxOut);
        else
            edge_compute_kernel<false><<<N_EDGES*2/256, 256, 0, stream>>>(
                xn3, iInd, jInd, posI, posJ, Q, mitg, flux16, nullptr);
        node_gather_kernel<<<N_NODES, 64, 0, stream>>>((const __fp16*)flux16, rowptr, xn3);
    }

    close_kernel<<<N_NODES/256, 256, 0, stream>>>(xn3, ws, out);
}